// Round 1
// baseline (657.036 us; speedup 1.0000x reference)
//
#include <hip/hip_runtime.h>
#include <hip/hip_bf16.h>
#include <math.h>

#define NN 1024
#define EMB 128
#define FC 512
#define NEDGE 523776   // 1024*1023/2
#define BM 64          // edge rows per block; NEDGE % BM == 0 (8184 blocks)

typedef __attribute__((ext_vector_type(4))) float f32x4;
typedef __attribute__((ext_vector_type(8))) short bf16x8;

__device__ __forceinline__ float bf2f(unsigned short u) {
  union { unsigned int i; float f; } v; v.i = ((unsigned int)u) << 16; return v.f;
}
__device__ __forceinline__ unsigned short f2bf(float f) {
  union { float g; unsigned int i; } v; v.g = f;
  unsigned int r = (v.i + 0x7fffu + ((v.i >> 16) & 1u)) >> 16;
  return (unsigned short)r;
}

__device__ __forceinline__ int cum_edges(int i) {
  // number of pairs (a,b), a<b, with a < i
  return i * NN - ((i * (i + 1)) >> 1);
}

// ---------------- setup kernels (tiny) ----------------

__global__ void k_cvt_weights(const float* __restrict__ lw0, const float* __restrict__ lw1,
                              unsigned short* __restrict__ w0b, unsigned short* __restrict__ w1b) {
  int t = blockIdx.x * 256 + threadIdx.x;
  if (t < FC * EMB) w0b[t] = f2bf(lw0[t]);
  int u = t - FC * EMB;
  if (u >= 0 && u < FC * FC) w1b[u] = f2bf(lw1[u]);
}

__global__ void k_mean_x(const float* __restrict__ x, float* __restrict__ mean0) {
  __shared__ float sx[256], sy[256];
  float ax = 0.f, ay = 0.f;
  for (int i = threadIdx.x; i < NN; i += 256) { ax += x[2*i]; ay += x[2*i+1]; }
  sx[threadIdx.x] = ax; sy[threadIdx.x] = ay;
  __syncthreads();
  for (int st = 128; st > 0; st >>= 1) {
    if (threadIdx.x < st) { sx[threadIdx.x] += sx[threadIdx.x+st]; sy[threadIdx.x] += sy[threadIdx.x+st]; }
    __syncthreads();
  }
  if (threadIdx.x == 0) { mean0[0] = sx[0] * (1.f/NN); mean0[1] = sy[0] * (1.f/NN); }
}

__global__ void k_sage0(const float* __restrict__ x, const float* __restrict__ wrel,
                        const float* __restrict__ brel, const float* __restrict__ wroot,
                        const float* __restrict__ mean0, float* __restrict__ h0) {
  int idx = blockIdx.x * 256 + threadIdx.x;   // 1024*128 threads
  int i = idx >> 7, c = idx & 127;
  float v = mean0[0]*wrel[2*c] + mean0[1]*wrel[2*c+1] + brel[c]
          + x[2*i]*wroot[2*c] + x[2*i+1]*wroot[2*c+1];
  h0[idx] = fmaxf(v, 0.f);
}

__global__ void k_mean_h0(const float* __restrict__ h0, float* __restrict__ mean1) {
  __shared__ float s[256];
  int c = blockIdx.x;
  float a = 0.f;
  for (int i = threadIdx.x; i < NN; i += 256) a += h0[i*EMB + c];
  s[threadIdx.x] = a;
  __syncthreads();
  for (int st = 128; st > 0; st >>= 1) {
    if (threadIdx.x < st) s[threadIdx.x] += s[threadIdx.x+st];
    __syncthreads();
  }
  if (threadIdx.x == 0) mean1[c] = s[0] * (1.f/NN);
}

__global__ void k_relc(const float* __restrict__ mean1, const float* __restrict__ wrel1,
                       const float* __restrict__ brel1, float* __restrict__ relc) {
  int c = threadIdx.x;  // 128 threads
  float a = brel1[c];
  #pragma unroll 8
  for (int k = 0; k < EMB; ++k) a += mean1[k] * wrel1[c*EMB + k];
  relc[c] = a;
}

__global__ void k_sage1(const float* __restrict__ h0, const float* __restrict__ wroot1,
                        const float* __restrict__ relc, unsigned short* __restrict__ hb) {
  int idx = blockIdx.x * 256 + threadIdx.x;   // 1024*128 threads
  int i = idx >> 7, c = idx & 127;
  const float4* hr = (const float4*)(h0 + i*EMB);
  const float4* wr = (const float4*)(wroot1 + c*EMB);
  float a = relc[c];
  #pragma unroll 8
  for (int k = 0; k < EMB/4; ++k) {
    float4 h = hr[k], w = wr[k];
    a += h.x*w.x + h.y*w.y + h.z*w.z + h.w*w.w;
  }
  hb[idx] = f2bf(fmaxf(a, 0.f));
}

// ---------------- fused edge MLP ----------------
// per block: BM=64 edge rows; e(64x128)->LDS; L0: e @ lw0^T (+b,relu) -> o0 LDS bf16;
// L1: o0 @ lw1^T (+b,relu) fused with L2 dot(lw2) + sigmoid.
// 4 waves, each owns a 128-wide N slice (8 n-tiles of 16), all 4 m-tiles.
__global__ __launch_bounds__(256, 2)
void k_edge_mlp(const unsigned short* __restrict__ hb,
                const unsigned short* __restrict__ w0b,
                const float* __restrict__ lb0,
                const unsigned short* __restrict__ w1b,
                const float* __restrict__ lb1,
                const float* __restrict__ lw2,
                const float* __restrict__ lb2,
                float* __restrict__ out) {
  __shared__ unsigned short e_lds[BM * EMB];   // 16 KB, XOR-swizzled; reused as f32 red buf
  __shared__ unsigned short o0_lds[BM * FC];   // 64 KB, XOR-swizzled

  const int tid  = threadIdx.x;
  const int lane = tid & 63;
  const int wv   = tid >> 6;
  const int l15  = lane & 15;
  const int l4   = lane >> 4;
  const int blk  = blockIdx.x;

  // ---- Phase A: gather h rows, build e tile ----
  {
    int r = tid >> 2;          // 0..63 local edge row
    int q = tid & 3;           // quarter of the 128-wide row
    int k = blk * BM + r;      // global edge id
    float fb = 2.0f * NN - 1.0f;
    float disc = fb*fb - 8.0f*(float)k;
    int i = (int)((fb - sqrtf(disc)) * 0.5f);
    if (i < 0) i = 0;
    if (i > NN-2) i = NN-2;
    while (cum_edges(i+1) <= k) ++i;
    while (cum_edges(i) > k) --i;
    int j = k - cum_edges(i) + i + 1;
    const bf16x8* hi = (const bf16x8*)(hb + i*EMB + q*32);
    const bf16x8* hj = (const bf16x8*)(hb + j*EMB + q*32);
    #pragma unroll
    for (int c = 0; c < 4; ++c) {
      bf16x8 a = hi[c], b = hj[c];
      bf16x8 p;
      #pragma unroll
      for (int u = 0; u < 8; ++u)
        p[u] = (short)f2bf(bf2f((unsigned short)a[u]) * bf2f((unsigned short)b[u]));
      int byt = (r * 256 + (q*32 + c*8)*2) ^ ((r & 7) << 4);
      *(bf16x8*)((char*)e_lds + byt) = p;
    }
  }
  __syncthreads();

  // ---- Phase B: layer0 (K=128) ----
  float lb0v[8];
  #pragma unroll
  for (int nt = 0; nt < 8; ++nt) lb0v[nt] = lb0[wv*128 + nt*16 + l15];

  f32x4 acc[4][8];
  #pragma unroll
  for (int mt = 0; mt < 4; ++mt)
    #pragma unroll
    for (int nt = 0; nt < 8; ++nt)
      acc[mt][nt] = (f32x4){0.f,0.f,0.f,0.f};

  #pragma unroll
  for (int kb = 0; kb < 4; ++kb) {
    bf16x8 af[4], bfr[8];
    #pragma unroll
    for (int mt = 0; mt < 4; ++mt) {
      int m = mt*16 + l15;
      int byt = (m * 256 + (kb*32 + l4*8)*2) ^ ((m & 7) << 4);
      af[mt] = *(const bf16x8*)((char*)e_lds + byt);
    }
    #pragma unroll
    for (int nt = 0; nt < 8; ++nt)
      bfr[nt] = *(const bf16x8*)(w0b + (wv*128 + nt*16 + l15)*EMB + kb*32 + l4*8);
    #pragma unroll
    for (int mt = 0; mt < 4; ++mt)
      #pragma unroll
      for (int nt = 0; nt < 8; ++nt)
        acc[mt][nt] = __builtin_amdgcn_mfma_f32_16x16x32_bf16(af[mt], bfr[nt], acc[mt][nt], 0, 0, 0);
  }

  // bias + relu + store o0 (bf16, swizzled). D layout: n=l15, m=l4*4+reg (m89-verified)
  #pragma unroll
  for (int mt = 0; mt < 4; ++mt)
    #pragma unroll
    for (int nt = 0; nt < 8; ++nt)
      #pragma unroll
      for (int rg = 0; rg < 4; ++rg) {
        int m = mt*16 + l4*4 + rg;
        int n = wv*128 + nt*16 + l15;
        float v = fmaxf(acc[mt][nt][rg] + lb0v[nt], 0.f);
        int byt = (m * 1024 + n*2) ^ ((m & 7) << 4);
        *(unsigned short*)((char*)o0_lds + byt) = f2bf(v);
      }
  __syncthreads();

  // ---- Phase C: layer1 (K=512) + fused layer2 ----
  #pragma unroll
  for (int mt = 0; mt < 4; ++mt)
    #pragma unroll
    for (int nt = 0; nt < 8; ++nt)
      acc[mt][nt] = (f32x4){0.f,0.f,0.f,0.f};

  for (int kb = 0; kb < 16; ++kb) {
    bf16x8 af[4], bfr[8];
    #pragma unroll
    for (int mt = 0; mt < 4; ++mt) {
      int m = mt*16 + l15;
      int byt = (m * 1024 + (kb*32 + l4*8)*2) ^ ((m & 7) << 4);
      af[mt] = *(const bf16x8*)((char*)o0_lds + byt);
    }
    #pragma unroll
    for (int nt = 0; nt < 8; ++nt)
      bfr[nt] = *(const bf16x8*)(w1b + (wv*128 + nt*16 + l15)*FC + kb*32 + l4*8);
    #pragma unroll
    for (int mt = 0; mt < 4; ++mt)
      #pragma unroll
      for (int nt = 0; nt < 8; ++nt)
        acc[mt][nt] = __builtin_amdgcn_mfma_f32_16x16x32_bf16(af[mt], bfr[nt], acc[mt][nt], 0, 0, 0);
  }

  float lb1v[8], lw2v[8];
  #pragma unroll
  for (int nt = 0; nt < 8; ++nt) {
    int n = wv*128 + nt*16 + l15;
    lb1v[nt] = lb1[n];
    lw2v[nt] = lw2[n];
  }

  float rsum[4][4];
  #pragma unroll
  for (int mt = 0; mt < 4; ++mt)
    #pragma unroll
    for (int rg = 0; rg < 4; ++rg) rsum[mt][rg] = 0.f;

  #pragma unroll
  for (int mt = 0; mt < 4; ++mt)
    #pragma unroll
    for (int nt = 0; nt < 8; ++nt)
      #pragma unroll
      for (int rg = 0; rg < 4; ++rg)
        rsum[mt][rg] += fmaxf(acc[mt][nt][rg] + lb1v[nt], 0.f) * lw2v[nt];

  // reduce over the 16 n-lanes
  #pragma unroll
  for (int d = 1; d < 16; d <<= 1)
    #pragma unroll
    for (int mt = 0; mt < 4; ++mt)
      #pragma unroll
      for (int rg = 0; rg < 4; ++rg)
        rsum[mt][rg] += __shfl_xor(rsum[mt][rg], d, 64);

  float* red = (float*)e_lds;   // e tile dead; reuse as 4x64 f32 partials
  if (l15 == 0) {
    #pragma unroll
    for (int mt = 0; mt < 4; ++mt)
      #pragma unroll
      for (int rg = 0; rg < 4; ++rg)
        red[wv*BM + mt*16 + l4*4 + rg] = rsum[mt][rg];
  }
  __syncthreads();

  if (tid < BM) {
    float v = red[tid] + red[BM+tid] + red[2*BM+tid] + red[3*BM+tid] + lb2[0];
    out[blk*BM + tid] = 1.0f / (1.0f + __expf(-v));
  }
}

// ---------------- launch ----------------
extern "C" void kernel_launch(void* const* d_in, const int* in_sizes, int n_in,
                              void* d_out, int out_size, void* d_ws, size_t ws_size,
                              hipStream_t stream) {
  const float* x      = (const float*)d_in[0];
  const float* wrel0  = (const float*)d_in[1];
  const float* brel0  = (const float*)d_in[2];
  const float* wroot0 = (const float*)d_in[3];
  const float* wrel1  = (const float*)d_in[4];
  const float* brel1  = (const float*)d_in[5];
  const float* wroot1 = (const float*)d_in[6];
  const float* lw0    = (const float*)d_in[7];
  const float* lb0    = (const float*)d_in[8];
  const float* lw1    = (const float*)d_in[9];
  const float* lb1    = (const float*)d_in[10];
  const float* lw2    = (const float*)d_in[11];
  const float* lb2    = (const float*)d_in[12];
  float* out = (float*)d_out;

  char* ws = (char*)d_ws;
  unsigned short* hb  = (unsigned short*)(ws);            // 1024*128 bf16  (262144 B)
  unsigned short* w0b = (unsigned short*)(ws + 262144);   // 512*128 bf16   (131072 B)
  unsigned short* w1b = (unsigned short*)(ws + 393216);   // 512*512 bf16   (524288 B)
  float* h0    = (float*)(ws + 917504);                   // 1024*128 f32   (524288 B)
  float* mean0 = (float*)(ws + 1441792);                  // 2 f32
  float* mean1 = (float*)(ws + 1441856);                  // 128 f32
  float* relc  = (float*)(ws + 1442368);                  // 128 f32

  hipLaunchKernelGGL(k_cvt_weights, dim3(1280), dim3(256), 0, stream, lw0, lw1, w0b, w1b);
  hipLaunchKernelGGL(k_mean_x,   dim3(1),    dim3(256), 0, stream, x, mean0);
  hipLaunchKernelGGL(k_sage0,    dim3(512),  dim3(256), 0, stream, x, wrel0, brel0, wroot0, mean0, h0);
  hipLaunchKernelGGL(k_mean_h0,  dim3(128),  dim3(256), 0, stream, h0, mean1);
  hipLaunchKernelGGL(k_relc,     dim3(1),    dim3(128), 0, stream, mean1, wrel1, brel1, relc);
  hipLaunchKernelGGL(k_sage1,    dim3(512),  dim3(256), 0, stream, h0, wroot1, relc, hb);
  hipLaunchKernelGGL(k_edge_mlp, dim3(NEDGE/BM), dim3(256), 0, stream,
                     hb, w0b, lb0, w1b, lb1, lw2, lb2, out);
}

// Round 2
// 649.606 us; speedup vs baseline: 1.0114x; 1.0114x over previous
//
#include <hip/hip_runtime.h>
#include <math.h>

#define NN 1024
#define EMB 128
#define FC 512
#define NEDGE 523776   // 1024*1023/2
#define BM 64          // edge rows per block; 8184 blocks

typedef __attribute__((ext_vector_type(4))) float f32x4;
typedef __attribute__((ext_vector_type(8))) short bf16x8;

__device__ __forceinline__ float bf2f(unsigned short u) {
  union { unsigned int i; float f; } v; v.i = ((unsigned int)u) << 16; return v.f;
}
__device__ __forceinline__ unsigned short f2bf(float f) {
  union { float g; unsigned int i; } v; v.g = f;
  return (unsigned short)((v.i + 0x7fffu + ((v.i >> 16) & 1u)) >> 16);
}
__device__ __forceinline__ int cum_edges(int i) { return i * NN - ((i * (i + 1)) >> 1); }

// ---------------- setup kernels (tiny) ----------------

__global__ void k_cvt_weights(const float* __restrict__ lw0, const float* __restrict__ lw1,
                              unsigned short* __restrict__ w0b, unsigned short* __restrict__ w1b) {
  int t = blockIdx.x * 256 + threadIdx.x;
  if (t < FC * EMB) w0b[t] = f2bf(lw0[t]);
  int u = t - FC * EMB;
  if (u >= 0 && u < FC * FC) w1b[u] = f2bf(lw1[u]);
}

__global__ void k_mean_x(const float* __restrict__ x, float* __restrict__ mean0) {
  __shared__ float sx[256], sy[256];
  float ax = 0.f, ay = 0.f;
  for (int i = threadIdx.x; i < NN; i += 256) { ax += x[2*i]; ay += x[2*i+1]; }
  sx[threadIdx.x] = ax; sy[threadIdx.x] = ay;
  __syncthreads();
  for (int st = 128; st > 0; st >>= 1) {
    if (threadIdx.x < st) { sx[threadIdx.x] += sx[threadIdx.x+st]; sy[threadIdx.x] += sy[threadIdx.x+st]; }
    __syncthreads();
  }
  if (threadIdx.x == 0) { mean0[0] = sx[0] * (1.f/NN); mean0[1] = sy[0] * (1.f/NN); }
}

__global__ void k_sage0(const float* __restrict__ x, const float* __restrict__ wrel,
                        const float* __restrict__ brel, const float* __restrict__ wroot,
                        const float* __restrict__ mean0, float* __restrict__ h0) {
  int idx = blockIdx.x * 256 + threadIdx.x;
  int i = idx >> 7, c = idx & 127;
  float v = mean0[0]*wrel[2*c] + mean0[1]*wrel[2*c+1] + brel[c]
          + x[2*i]*wroot[2*c] + x[2*i+1]*wroot[2*c+1];
  h0[idx] = fmaxf(v, 0.f);
}

__global__ void k_mean_h0(const float* __restrict__ h0, float* __restrict__ mean1) {
  __shared__ float s[256];
  int c = blockIdx.x;
  float a = 0.f;
  for (int i = threadIdx.x; i < NN; i += 256) a += h0[i*EMB + c];
  s[threadIdx.x] = a;
  __syncthreads();
  for (int st = 128; st > 0; st >>= 1) {
    if (threadIdx.x < st) s[threadIdx.x] += s[threadIdx.x+st];
    __syncthreads();
  }
  if (threadIdx.x == 0) mean1[c] = s[0] * (1.f/NN);
}

__global__ void k_relc(const float* __restrict__ mean1, const float* __restrict__ wrel1,
                       const float* __restrict__ brel1, float* __restrict__ relc) {
  int c = threadIdx.x;
  float a = brel1[c];
  #pragma unroll 8
  for (int k = 0; k < EMB; ++k) a += mean1[k] * wrel1[c*EMB + k];
  relc[c] = a;
}

__global__ void k_sage1(const float* __restrict__ h0, const float* __restrict__ wroot1,
                        const float* __restrict__ relc, unsigned short* __restrict__ hb) {
  int idx = blockIdx.x * 256 + threadIdx.x;
  int i = idx >> 7, c = idx & 127;
  const float4* hr = (const float4*)(h0 + i*EMB);
  const float4* wr = (const float4*)(wroot1 + c*EMB);
  float a = relc[c];
  #pragma unroll 8
  for (int k = 0; k < EMB/4; ++k) {
    float4 h = hr[k], w = wr[k];
    a += h.x*w.x + h.y*w.y + h.z*w.z + h.w*w.w;
  }
  hb[idx] = f2bf(fmaxf(a, 0.f));
}

// ---------------- fused edge MLP ----------------
// Swapped MFMA roles: A = weights (rows = fc), B = activations (cols = edges).
// D layout: fc = l4*4+reg (4 consecutive -> packed b64 o0 store), edge = l15.
__global__ __launch_bounds__(256, 2)
void k_edge_mlp(const unsigned short* __restrict__ hb,
                const unsigned short* __restrict__ w0b,
                const float* __restrict__ lb0,
                const unsigned short* __restrict__ w1b,
                const float* __restrict__ lb1,
                const float* __restrict__ lw2,
                const float* __restrict__ lb2,
                float* __restrict__ out) {
  __shared__ __align__(16) unsigned short e_lds[BM * EMB];   // 16 KB, swz (edge&7)<<4
  __shared__ __align__(16) unsigned short o0_lds[BM * FC];   // 64 KB, swz (edge&7)<<4

  const int tid  = threadIdx.x;
  const int lane = tid & 63;
  const int wv   = tid >> 6;
  const int l15  = lane & 15;
  const int l4   = lane >> 4;
  const int blk  = blockIdx.x;
  const int fcb  = wv * 128;           // this wave's fc slice (both layers)

  bf16x8 a0[8], a1[8], b0[4], b1[4];

  // issue-early: layer0 A-frags for kb=0 (global, independent of LDS)
  #pragma unroll
  for (int f = 0; f < 8; ++f)
    a0[f] = *(const bf16x8*)(w0b + (fcb + f*16 + l15)*EMB + l4*8);

  // ---- Phase A: gather h rows, build e tile ----
  {
    int r = tid >> 2, q = tid & 3;
    int k = blk * BM + r;
    float fb = 2.0f * NN - 1.0f;
    float disc = fb*fb - 8.0f*(float)k;
    int i = (int)((fb - sqrtf(disc)) * 0.5f);
    if (i < 0) i = 0;
    if (i > NN-2) i = NN-2;
    while (cum_edges(i+1) <= k) ++i;
    while (cum_edges(i) > k) --i;
    int j = k - cum_edges(i) + i + 1;
    const bf16x8* hi = (const bf16x8*)(hb + i*EMB + q*32);
    const bf16x8* hj = (const bf16x8*)(hb + j*EMB + q*32);
    #pragma unroll
    for (int c = 0; c < 4; ++c) {
      bf16x8 a = hi[c], b = hj[c];
      bf16x8 p;
      #pragma unroll
      for (int u = 0; u < 8; ++u)
        p[u] = (short)f2bf(bf2f((unsigned short)a[u]) * bf2f((unsigned short)b[u]));
      int byt = (r*256 + (q*32 + c*8)*2) ^ ((r & 7) << 4);
      *(bf16x8*)((char*)e_lds + byt) = p;
    }
  }
  __syncthreads();

  // ---- Layer0: K=128, A=W0, B=e ----
  f32x4 acc[4][8];
  #pragma unroll
  for (int e = 0; e < 4; ++e)
    #pragma unroll
    for (int f = 0; f < 8; ++f)
      acc[e][f] = (f32x4){0.f, 0.f, 0.f, 0.f};

  #pragma unroll
  for (int e = 0; e < 4; ++e) {
    int ed = e*16 + l15;
    b0[e] = *(const bf16x8*)((const char*)e_lds + ((ed*256 + l4*16) ^ ((ed & 7) << 4)));
  }

  #pragma unroll
  for (int kb = 0; kb < 4; kb += 2) {
    #pragma unroll
    for (int f = 0; f < 8; ++f)
      a1[f] = *(const bf16x8*)(w0b + (fcb + f*16 + l15)*EMB + (kb+1)*32 + l4*8);
    #pragma unroll
    for (int e = 0; e < 4; ++e) {
      int ed = e*16 + l15;
      b1[e] = *(const bf16x8*)((const char*)e_lds + ((ed*256 + (kb+1)*64 + l4*16) ^ ((ed & 7) << 4)));
    }
    __builtin_amdgcn_s_setprio(1);
    #pragma unroll
    for (int e = 0; e < 4; ++e)
      #pragma unroll
      for (int f = 0; f < 8; ++f)
        acc[e][f] = __builtin_amdgcn_mfma_f32_16x16x32_bf16(a0[f], b0[e], acc[e][f], 0, 0, 0);
    __builtin_amdgcn_s_setprio(0);
    if (kb + 2 < 4) {
      #pragma unroll
      for (int f = 0; f < 8; ++f)
        a0[f] = *(const bf16x8*)(w0b + (fcb + f*16 + l15)*EMB + (kb+2)*32 + l4*8);
      #pragma unroll
      for (int e = 0; e < 4; ++e) {
        int ed = e*16 + l15;
        b0[e] = *(const bf16x8*)((const char*)e_lds + ((ed*256 + (kb+2)*64 + l4*16) ^ ((ed & 7) << 4)));
      }
    }
    __builtin_amdgcn_s_setprio(1);
    #pragma unroll
    for (int e = 0; e < 4; ++e)
      #pragma unroll
      for (int f = 0; f < 8; ++f)
        acc[e][f] = __builtin_amdgcn_mfma_f32_16x16x32_bf16(a1[f], b1[e], acc[e][f], 0, 0, 0);
    __builtin_amdgcn_s_setprio(0);
  }

  // ---- bias + relu + packed o0 store; issue-early layer1 kb=0 A-frags ----
  {
    float4 bv[8];
    #pragma unroll
    for (int f = 0; f < 8; ++f) bv[f] = *(const float4*)(lb0 + fcb + f*16 + l4*4);
    #pragma unroll
    for (int f = 0; f < 8; ++f)
      a0[f] = *(const bf16x8*)(w1b + (fcb + f*16 + l15)*FC + l4*8);   // layer1 kb=0
    #pragma unroll
    for (int e = 0; e < 4; ++e) {
      int ed = e*16 + l15;
      #pragma unroll
      for (int f = 0; f < 8; ++f) {
        float v0 = fmaxf(acc[e][f][0] + bv[f].x, 0.f);
        float v1 = fmaxf(acc[e][f][1] + bv[f].y, 0.f);
        float v2 = fmaxf(acc[e][f][2] + bv[f].z, 0.f);
        float v3 = fmaxf(acc[e][f][3] + bv[f].w, 0.f);
        unsigned int lo = (unsigned int)f2bf(v0) | ((unsigned int)f2bf(v1) << 16);
        unsigned int hi = (unsigned int)f2bf(v2) | ((unsigned int)f2bf(v3) << 16);
        int byt = (ed*1024 + (fcb + f*16 + l4*4)*2) ^ ((ed & 7) << 4);
        *(uint2*)((char*)o0_lds + byt) = make_uint2(lo, hi);
      }
    }
  }
  __syncthreads();

  // ---- Layer1: K=512, A=W1, B=o0 ----
  #pragma unroll
  for (int e = 0; e < 4; ++e)
    #pragma unroll
    for (int f = 0; f < 8; ++f)
      acc[e][f] = (f32x4){0.f, 0.f, 0.f, 0.f};

  #pragma unroll
  for (int e = 0; e < 4; ++e) {
    int ed = e*16 + l15;
    b0[e] = *(const bf16x8*)((const char*)o0_lds + ((ed*1024 + l4*16) ^ ((ed & 7) << 4)));
  }

  #pragma unroll
  for (int kb = 0; kb < 16; kb += 2) {
    #pragma unroll
    for (int f = 0; f < 8; ++f)
      a1[f] = *(const bf16x8*)(w1b + (fcb + f*16 + l15)*FC + (kb+1)*32 + l4*8);
    #pragma unroll
    for (int e = 0; e < 4; ++e) {
      int ed = e*16 + l15;
      b1[e] = *(const bf16x8*)((const char*)o0_lds + ((ed*1024 + (kb+1)*64 + l4*16) ^ ((ed & 7) << 4)));
    }
    __builtin_amdgcn_s_setprio(1);
    #pragma unroll
    for (int e = 0; e < 4; ++e)
      #pragma unroll
      for (int f = 0; f < 8; ++f)
        acc[e][f] = __builtin_amdgcn_mfma_f32_16x16x32_bf16(a0[f], b0[e], acc[e][f], 0, 0, 0);
    __builtin_amdgcn_s_setprio(0);
    if (kb + 2 < 16) {
      #pragma unroll
      for (int f = 0; f < 8; ++f)
        a0[f] = *(const bf16x8*)(w1b + (fcb + f*16 + l15)*FC + (kb+2)*32 + l4*8);
      #pragma unroll
      for (int e = 0; e < 4; ++e) {
        int ed = e*16 + l15;
        b0[e] = *(const bf16x8*)((const char*)o0_lds + ((ed*1024 + (kb+2)*64 + l4*16) ^ ((ed & 7) << 4)));
      }
    }
    __builtin_amdgcn_s_setprio(1);
    #pragma unroll
    for (int e = 0; e < 4; ++e)
      #pragma unroll
      for (int f = 0; f < 8; ++f)
        acc[e][f] = __builtin_amdgcn_mfma_f32_16x16x32_bf16(a1[f], b1[e], acc[e][f], 0, 0, 0);
    __builtin_amdgcn_s_setprio(0);
  }

  // ---- fused layer2 + sigmoid ----
  {
    float4 l1v[8], l2v[8];
    #pragma unroll
    for (int f = 0; f < 8; ++f) {
      l1v[f] = *(const float4*)(lb1 + fcb + f*16 + l4*4);
      l2v[f] = *(const float4*)(lw2 + fcb + f*16 + l4*4);
    }
    float rs[4] = {0.f, 0.f, 0.f, 0.f};
    #pragma unroll
    for (int e = 0; e < 4; ++e)
      #pragma unroll
      for (int f = 0; f < 8; ++f) {
        rs[e] += fmaxf(acc[e][f][0] + l1v[f].x, 0.f) * l2v[f].x;
        rs[e] += fmaxf(acc[e][f][1] + l1v[f].y, 0.f) * l2v[f].y;
        rs[e] += fmaxf(acc[e][f][2] + l1v[f].z, 0.f) * l2v[f].z;
        rs[e] += fmaxf(acc[e][f][3] + l1v[f].w, 0.f) * l2v[f].w;
      }
    #pragma unroll
    for (int e = 0; e < 4; ++e) {
      rs[e] += __shfl_xor(rs[e], 16, 64);
      rs[e] += __shfl_xor(rs[e], 32, 64);
    }
    float* red = (float*)e_lds;   // e tile dead
    if (l4 == 0) {
      #pragma unroll
      for (int e = 0; e < 4; ++e) red[wv*BM + e*16 + l15] = rs[e];
    }
  }
  __syncthreads();

  if (tid < BM) {
    float v = ((float*)e_lds)[tid] + ((float*)e_lds)[BM+tid]
            + ((float*)e_lds)[2*BM+tid] + ((float*)e_lds)[3*BM+tid] + lb2[0];
    out[blk*BM + tid] = 1.0f / (1.0f + __expf(-v));
  }
}

// ---------------- launch ----------------
extern "C" void kernel_launch(void* const* d_in, const int* in_sizes, int n_in,
                              void* d_out, int out_size, void* d_ws, size_t ws_size,
                              hipStream_t stream) {
  const float* x      = (const float*)d_in[0];
  const float* wrel0  = (const float*)d_in[1];
  const float* brel0  = (const float*)d_in[2];
  const float* wroot0 = (const float*)d_in[3];
  const float* wrel1  = (const float*)d_in[4];
  const float* brel1  = (const float*)d_in[5];
  const float* wroot1 = (const float*)d_in[6];
  const float* lw0    = (const float*)d_in[7];
  const float* lb0    = (const float*)d_in[8];
  const float* lw1    = (const float*)d_in[9];
  const float* lb1    = (const float*)d_in[10];
  const float* lw2    = (const float*)d_in[11];
  const float* lb2    = (const float*)d_in[12];
  float* out = (float*)d_out;

  char* ws = (char*)d_ws;
  unsigned short* hb  = (unsigned short*)(ws);            // 1024*128 bf16
  unsigned short* w0b = (unsigned short*)(ws + 262144);   // 512*128 bf16
  unsigned short* w1b = (unsigned short*)(ws + 393216);   // 512*512 bf16
  float* h0    = (float*)(ws + 917504);                   // 1024*128 f32
  float* mean0 = (float*)(ws + 1441792);
  float* mean1 = (float*)(ws + 1441856);
  float* relc  = (float*)(ws + 1442368);

  hipLaunchKernelGGL(k_cvt_weights, dim3(1280), dim3(256), 0, stream, lw0, lw1, w0b, w1b);
  hipLaunchKernelGGL(k_mean_x,   dim3(1),    dim3(256), 0, stream, x, mean0);
  hipLaunchKernelGGL(k_sage0,    dim3(512),  dim3(256), 0, stream, x, wrel0, brel0, wroot0, mean0, h0);
  hipLaunchKernelGGL(k_mean_h0,  dim3(128),  dim3(256), 0, stream, h0, mean1);
  hipLaunchKernelGGL(k_relc,     dim3(1),    dim3(128), 0, stream, mean1, wrel1, brel1, relc);
  hipLaunchKernelGGL(k_sage1,    dim3(512),  dim3(256), 0, stream, h0, wroot1, relc, hb);
  hipLaunchKernelGGL(k_edge_mlp, dim3(NEDGE/BM), dim3(256), 0, stream,
                     hb, w0b, lb0, w1b, lb1, lw2, lb2, out);
}

// Round 3
// 639.323 us; speedup vs baseline: 1.0277x; 1.0161x over previous
//
#include <hip/hip_runtime.h>
#include <math.h>

#define NN 1024
#define EMB 128
#define FC 512
#define NEDGE 523776   // 1024*1023/2
#define BM 64          // edge rows per block; 8184 blocks

typedef __attribute__((ext_vector_type(4))) float f32x4;
typedef __attribute__((ext_vector_type(8))) short bf16x8;

__device__ __forceinline__ float bf2f(unsigned short u) {
  union { unsigned int i; float f; } v; v.i = ((unsigned int)u) << 16; return v.f;
}
__device__ __forceinline__ unsigned short f2bf(float f) {
  union { float g; unsigned int i; } v; v.g = f;
  return (unsigned short)((v.i + 0x7fffu + ((v.i >> 16) & 1u)) >> 16);
}
__device__ __forceinline__ int cum_edges(int i) { return i * NN - ((i * (i + 1)) >> 1); }

// ---------------- setup kernels (tiny) ----------------

__global__ void k_cvt_weights(const float* __restrict__ lw0, const float* __restrict__ lw1,
                              unsigned short* __restrict__ w0b, unsigned short* __restrict__ w1b) {
  int t = blockIdx.x * 256 + threadIdx.x;
  if (t < FC * EMB) w0b[t] = f2bf(lw0[t]);
  int u = t - FC * EMB;
  if (u >= 0 && u < FC * FC) w1b[u] = f2bf(lw1[u]);
}

__global__ void k_mean_x(const float* __restrict__ x, float* __restrict__ mean0) {
  __shared__ float sx[256], sy[256];
  float ax = 0.f, ay = 0.f;
  for (int i = threadIdx.x; i < NN; i += 256) { ax += x[2*i]; ay += x[2*i+1]; }
  sx[threadIdx.x] = ax; sy[threadIdx.x] = ay;
  __syncthreads();
  for (int st = 128; st > 0; st >>= 1) {
    if (threadIdx.x < st) { sx[threadIdx.x] += sx[threadIdx.x+st]; sy[threadIdx.x] += sy[threadIdx.x+st]; }
    __syncthreads();
  }
  if (threadIdx.x == 0) { mean0[0] = sx[0] * (1.f/NN); mean0[1] = sy[0] * (1.f/NN); }
}

__global__ void k_sage0(const float* __restrict__ x, const float* __restrict__ wrel,
                        const float* __restrict__ brel, const float* __restrict__ wroot,
                        const float* __restrict__ mean0, float* __restrict__ h0) {
  int idx = blockIdx.x * 256 + threadIdx.x;
  int i = idx >> 7, c = idx & 127;
  float v = mean0[0]*wrel[2*c] + mean0[1]*wrel[2*c+1] + brel[c]
          + x[2*i]*wroot[2*c] + x[2*i+1]*wroot[2*c+1];
  h0[idx] = fmaxf(v, 0.f);
}

__global__ void k_mean_h0(const float* __restrict__ h0, float* __restrict__ mean1) {
  __shared__ float s[256];
  int c = blockIdx.x;
  float a = 0.f;
  for (int i = threadIdx.x; i < NN; i += 256) a += h0[i*EMB + c];
  s[threadIdx.x] = a;
  __syncthreads();
  for (int st = 128; st > 0; st >>= 1) {
    if (threadIdx.x < st) s[threadIdx.x] += s[threadIdx.x+st];
    __syncthreads();
  }
  if (threadIdx.x == 0) mean1[c] = s[0] * (1.f/NN);
}

__global__ void k_relc(const float* __restrict__ mean1, const float* __restrict__ wrel1,
                       const float* __restrict__ brel1, float* __restrict__ relc) {
  int c = threadIdx.x;
  float a = brel1[c];
  #pragma unroll 8
  for (int k = 0; k < EMB; ++k) a += mean1[k] * wrel1[c*EMB + k];
  relc[c] = a;
}

__global__ void k_sage1(const float* __restrict__ h0, const float* __restrict__ wroot1,
                        const float* __restrict__ relc, unsigned short* __restrict__ hb) {
  int idx = blockIdx.x * 256 + threadIdx.x;
  int i = idx >> 7, c = idx & 127;
  const float4* hr = (const float4*)(h0 + i*EMB);
  const float4* wr = (const float4*)(wroot1 + c*EMB);
  float a = relc[c];
  #pragma unroll 8
  for (int k = 0; k < EMB/4; ++k) {
    float4 h = hr[k], w = wr[k];
    a += h.x*w.x + h.y*w.y + h.z*w.z + h.w*w.w;
  }
  hb[idx] = f2bf(fmaxf(a, 0.f));
}

// ---------------- fused edge MLP ----------------
// 512 threads = 8 waves; wave w owns fc slice [w*64, w*64+64) in BOTH layers.
// A = weights (rows = fc), B = activations (cols = edges).
// D layout: fc = l4*4+reg (packed b64 o0 store), edge = l15.
// LDS 80KB -> 2 blocks/CU -> 16 waves/CU -> 4 waves/SIMD (needs <=128 VGPR).
__global__ __launch_bounds__(512, 4)
void k_edge_mlp(const unsigned short* __restrict__ hb,
                const unsigned short* __restrict__ w0b,
                const float* __restrict__ lb0,
                const unsigned short* __restrict__ w1b,
                const float* __restrict__ lb1,
                const float* __restrict__ lw2,
                const float* __restrict__ lb2,
                float* __restrict__ out) {
  __shared__ __align__(16) unsigned short e_lds[BM * EMB];   // 16 KB, swz (edge&7)<<4
  __shared__ __align__(16) unsigned short o0_lds[BM * FC];   // 64 KB, swz (edge&7)<<4

  const int tid  = threadIdx.x;
  const int lane = tid & 63;
  const int wv   = tid >> 6;           // 0..7
  const int l15  = lane & 15;
  const int l4   = lane >> 4;
  const int blk  = blockIdx.x;
  const int fcb  = wv * 64;            // this wave's fc slice (both layers)

  // ---- Phase A: gather h rows, build e tile ----
  {
    int r = tid >> 3, q = tid & 7;     // r: edge row 0..63, q: 16-elem chunk
    int k = blk * BM + r;
    float fb = 2.0f * NN - 1.0f;
    float disc = fb*fb - 8.0f*(float)k;
    int i = (int)((fb - sqrtf(disc)) * 0.5f);
    if (i < 0) i = 0;
    if (i > NN-2) i = NN-2;
    while (cum_edges(i+1) <= k) ++i;
    while (cum_edges(i) > k) --i;
    int j = k - cum_edges(i) + i + 1;
    const bf16x8* hi = (const bf16x8*)(hb + i*EMB + q*16);
    const bf16x8* hj = (const bf16x8*)(hb + j*EMB + q*16);
    #pragma unroll
    for (int c = 0; c < 2; ++c) {
      bf16x8 a = hi[c], b = hj[c];
      bf16x8 p;
      #pragma unroll
      for (int u = 0; u < 8; ++u)
        p[u] = (short)f2bf(bf2f((unsigned short)a[u]) * bf2f((unsigned short)b[u]));
      int byt = (r*256 + (q*16 + c*8)*2) ^ ((r & 7) << 4);
      *(bf16x8*)((char*)e_lds + byt) = p;
    }
  }
  __syncthreads();

  // ---- Layer0: K=128, A=W0 (4 f-tiles of 16 fc), B=e (4 e-tiles) ----
  f32x4 acc[4][4];
  #pragma unroll
  for (int e = 0; e < 4; ++e)
    #pragma unroll
    for (int f = 0; f < 4; ++f)
      acc[e][f] = (f32x4){0.f, 0.f, 0.f, 0.f};

  #pragma unroll
  for (int kb = 0; kb < 4; ++kb) {
    bf16x8 af[4], bf[4];
    #pragma unroll
    for (int f = 0; f < 4; ++f)
      af[f] = *(const bf16x8*)(w0b + (fcb + f*16 + l15)*EMB + kb*32 + l4*8);
    #pragma unroll
    for (int e = 0; e < 4; ++e) {
      int ed = e*16 + l15;
      bf[e] = *(const bf16x8*)((const char*)e_lds + ((ed*256 + kb*64 + l4*16) ^ ((ed & 7) << 4)));
    }
    __builtin_amdgcn_s_setprio(1);
    #pragma unroll
    for (int e = 0; e < 4; ++e)
      #pragma unroll
      for (int f = 0; f < 4; ++f)
        acc[e][f] = __builtin_amdgcn_mfma_f32_16x16x32_bf16(af[f], bf[e], acc[e][f], 0, 0, 0);
    __builtin_amdgcn_s_setprio(0);
  }

  // ---- bias + relu + packed o0 store ----
  {
    float4 bv[4];
    #pragma unroll
    for (int f = 0; f < 4; ++f) bv[f] = *(const float4*)(lb0 + fcb + f*16 + l4*4);
    #pragma unroll
    for (int e = 0; e < 4; ++e) {
      int ed = e*16 + l15;
      #pragma unroll
      for (int f = 0; f < 4; ++f) {
        float v0 = fmaxf(acc[e][f][0] + bv[f].x, 0.f);
        float v1 = fmaxf(acc[e][f][1] + bv[f].y, 0.f);
        float v2 = fmaxf(acc[e][f][2] + bv[f].z, 0.f);
        float v3 = fmaxf(acc[e][f][3] + bv[f].w, 0.f);
        unsigned int lo = (unsigned int)f2bf(v0) | ((unsigned int)f2bf(v1) << 16);
        unsigned int hi = (unsigned int)f2bf(v2) | ((unsigned int)f2bf(v3) << 16);
        int byt = (ed*1024 + (fcb + f*16 + l4*4)*2) ^ ((ed & 7) << 4);
        *(uint2*)((char*)o0_lds + byt) = make_uint2(lo, hi);
      }
    }
  }
  __syncthreads();

  // ---- Layer1: K=512, A=W1, B=o0 ----
  #pragma unroll
  for (int e = 0; e < 4; ++e)
    #pragma unroll
    for (int f = 0; f < 4; ++f)
      acc[e][f] = (f32x4){0.f, 0.f, 0.f, 0.f};

  #pragma unroll
  for (int kb = 0; kb < 16; ++kb) {
    bf16x8 af[4], bf[4];
    #pragma unroll
    for (int f = 0; f < 4; ++f)
      af[f] = *(const bf16x8*)(w1b + (fcb + f*16 + l15)*FC + kb*32 + l4*8);
    #pragma unroll
    for (int e = 0; e < 4; ++e) {
      int ed = e*16 + l15;
      bf[e] = *(const bf16x8*)((const char*)o0_lds + ((ed*1024 + kb*64 + l4*16) ^ ((ed & 7) << 4)));
    }
    __builtin_amdgcn_s_setprio(1);
    #pragma unroll
    for (int e = 0; e < 4; ++e)
      #pragma unroll
      for (int f = 0; f < 4; ++f)
        acc[e][f] = __builtin_amdgcn_mfma_f32_16x16x32_bf16(af[f], bf[e], acc[e][f], 0, 0, 0);
    __builtin_amdgcn_s_setprio(0);
  }

  // ---- fused layer2 + sigmoid ----
  {
    float4 l1v[4], l2v[4];
    #pragma unroll
    for (int f = 0; f < 4; ++f) {
      l1v[f] = *(const float4*)(lb1 + fcb + f*16 + l4*4);
      l2v[f] = *(const float4*)(lw2 + fcb + f*16 + l4*4);
    }
    float rs[4] = {0.f, 0.f, 0.f, 0.f};
    #pragma unroll
    for (int e = 0; e < 4; ++e)
      #pragma unroll
      for (int f = 0; f < 4; ++f) {
        rs[e] += fmaxf(acc[e][f][0] + l1v[f].x, 0.f) * l2v[f].x;
        rs[e] += fmaxf(acc[e][f][1] + l1v[f].y, 0.f) * l2v[f].y;
        rs[e] += fmaxf(acc[e][f][2] + l1v[f].z, 0.f) * l2v[f].z;
        rs[e] += fmaxf(acc[e][f][3] + l1v[f].w, 0.f) * l2v[f].w;
      }
    #pragma unroll
    for (int e = 0; e < 4; ++e) {
      rs[e] += __shfl_xor(rs[e], 16, 64);
      rs[e] += __shfl_xor(rs[e], 32, 64);
    }
    float* red = (float*)e_lds;   // e tile dead (consumed before o0 barrier)
    if (l4 == 0) {
      #pragma unroll
      for (int e = 0; e < 4; ++e) red[wv*BM + e*16 + l15] = rs[e];
    }
  }
  __syncthreads();

  if (tid < BM) {
    const float* red = (const float*)e_lds;
    float v = lb2[0];
    #pragma unroll
    for (int w = 0; w < 8; ++w) v += red[w*BM + tid];
    out[blk*BM + tid] = 1.0f / (1.0f + __expf(-v));
  }
}

// ---------------- launch ----------------
extern "C" void kernel_launch(void* const* d_in, const int* in_sizes, int n_in,
                              void* d_out, int out_size, void* d_ws, size_t ws_size,
                              hipStream_t stream) {
  const float* x      = (const float*)d_in[0];
  const float* wrel0  = (const float*)d_in[1];
  const float* brel0  = (const float*)d_in[2];
  const float* wroot0 = (const float*)d_in[3];
  const float* wrel1  = (const float*)d_in[4];
  const float* brel1  = (const float*)d_in[5];
  const float* wroot1 = (const float*)d_in[6];
  const float* lw0    = (const float*)d_in[7];
  const float* lb0    = (const float*)d_in[8];
  const float* lw1    = (const float*)d_in[9];
  const float* lb1    = (const float*)d_in[10];
  const float* lw2    = (const float*)d_in[11];
  const float* lb2    = (const float*)d_in[12];
  float* out = (float*)d_out;

  char* ws = (char*)d_ws;
  unsigned short* hb  = (unsigned short*)(ws);            // 1024*128 bf16
  unsigned short* w0b = (unsigned short*)(ws + 262144);   // 512*128 bf16
  unsigned short* w1b = (unsigned short*)(ws + 393216);   // 512*512 bf16
  float* h0    = (float*)(ws + 917504);                   // 1024*128 f32
  float* mean0 = (float*)(ws + 1441792);
  float* mean1 = (float*)(ws + 1441856);
  float* relc  = (float*)(ws + 1442368);

  hipLaunchKernelGGL(k_cvt_weights, dim3(1280), dim3(256), 0, stream, lw0, lw1, w0b, w1b);
  hipLaunchKernelGGL(k_mean_x,   dim3(1),    dim3(256), 0, stream, x, mean0);
  hipLaunchKernelGGL(k_sage0,    dim3(512),  dim3(256), 0, stream, x, wrel0, brel0, wroot0, mean0, h0);
  hipLaunchKernelGGL(k_mean_h0,  dim3(128),  dim3(256), 0, stream, h0, mean1);
  hipLaunchKernelGGL(k_relc,     dim3(1),    dim3(128), 0, stream, mean1, wrel1, brel1, relc);
  hipLaunchKernelGGL(k_sage1,    dim3(512),  dim3(256), 0, stream, h0, wroot1, relc, hb);
  hipLaunchKernelGGL(k_edge_mlp, dim3(NEDGE/BM), dim3(512), 0, stream,
                     hb, w0b, lb0, w1b, lb1, lw2, lb2, out);
}

// Round 4
// 370.880 us; speedup vs baseline: 1.7716x; 1.7238x over previous
//
#include <hip/hip_runtime.h>
#include <math.h>

#define NN 1024
#define EMB 128
#define FC 512
#define NEDGE 523776   // 1024*1023/2
#define BM 64          // edge rows per block; 8184 blocks

typedef __attribute__((ext_vector_type(4))) float f32x4;
typedef __attribute__((ext_vector_type(8))) short bf16x8;

__device__ __forceinline__ float bf2f(unsigned short u) {
  union { unsigned int i; float f; } v; v.i = ((unsigned int)u) << 16; return v.f;
}
__device__ __forceinline__ unsigned short f2bf(float f) {
  union { float g; unsigned int i; } v; v.g = f;
  return (unsigned short)((v.i + 0x7fffu + ((v.i >> 16) & 1u)) >> 16);
}
__device__ __forceinline__ int cum_edges(int i) { return i * NN - ((i * (i + 1)) >> 1); }

// async 4x16B-per-lane stage: 1 KB per instr, 4 KB total (one wave weight slice)
__device__ __forceinline__ void stage4(const unsigned short* src, unsigned short* dst, int lane) {
  #pragma unroll
  for (int i = 0; i < 4; ++i)
    __builtin_amdgcn_global_load_lds(
        (const __attribute__((address_space(1))) void*)(src + i*512 + lane*8),
        (__attribute__((address_space(3))) void*)(dst + i*512 + lane*8),
        16, 0, 0);
}

// ---------------- setup kernels (tiny) ----------------
// Weights pre-tiled for the DMA pipeline:
// w0t[f8(8)][kb(4)][ko(4)][fl(64)][e(8)]  = W0[f8*64+fl][kb*32+ko*8+e]
// w1t[f8(8)][kb(16)][ko(4)][fl(64)][e(8)] = W1[f8*64+fl][kb*32+ko*8+e]
__global__ void k_cvt_weights(const float* __restrict__ lw0, const float* __restrict__ lw1,
                              unsigned short* __restrict__ w0t, unsigned short* __restrict__ w1t) {
  int t = blockIdx.x * 256 + threadIdx.x;   // 1280 blocks * 256 = 327680 exact
  if (t < 65536) {
    int e = t & 7, fl = (t >> 3) & 63, ko = (t >> 9) & 3, kb = (t >> 11) & 3, f8 = (t >> 13) & 7;
    w0t[t] = f2bf(lw0[(f8*64 + fl)*EMB + kb*32 + ko*8 + e]);
  } else {
    int u = t - 65536;
    int e = u & 7, fl = (u >> 3) & 63, ko = (u >> 9) & 3, kb = (u >> 11) & 15, f8 = (u >> 15) & 7;
    w1t[u] = f2bf(lw1[(f8*64 + fl)*FC + kb*32 + ko*8 + e]);
  }
}

__global__ void k_mean_x(const float* __restrict__ x, float* __restrict__ mean0) {
  __shared__ float sx[256], sy[256];
  float ax = 0.f, ay = 0.f;
  for (int i = threadIdx.x; i < NN; i += 256) { ax += x[2*i]; ay += x[2*i+1]; }
  sx[threadIdx.x] = ax; sy[threadIdx.x] = ay;
  __syncthreads();
  for (int st = 128; st > 0; st >>= 1) {
    if (threadIdx.x < st) { sx[threadIdx.x] += sx[threadIdx.x+st]; sy[threadIdx.x] += sy[threadIdx.x+st]; }
    __syncthreads();
  }
  if (threadIdx.x == 0) { mean0[0] = sx[0] * (1.f/NN); mean0[1] = sy[0] * (1.f/NN); }
}

__global__ void k_sage0(const float* __restrict__ x, const float* __restrict__ wrel,
                        const float* __restrict__ brel, const float* __restrict__ wroot,
                        const float* __restrict__ mean0, float* __restrict__ h0) {
  int idx = blockIdx.x * 256 + threadIdx.x;
  int i = idx >> 7, c = idx & 127;
  float v = mean0[0]*wrel[2*c] + mean0[1]*wrel[2*c+1] + brel[c]
          + x[2*i]*wroot[2*c] + x[2*i+1]*wroot[2*c+1];
  h0[idx] = fmaxf(v, 0.f);
}

__global__ void k_mean_h0(const float* __restrict__ h0, float* __restrict__ mean1) {
  __shared__ float s[256];
  int c = blockIdx.x;
  float a = 0.f;
  for (int i = threadIdx.x; i < NN; i += 256) a += h0[i*EMB + c];
  s[threadIdx.x] = a;
  __syncthreads();
  for (int st = 128; st > 0; st >>= 1) {
    if (threadIdx.x < st) s[threadIdx.x] += s[threadIdx.x+st];
    __syncthreads();
  }
  if (threadIdx.x == 0) mean1[c] = s[0] * (1.f/NN);
}

__global__ void k_relc(const float* __restrict__ mean1, const float* __restrict__ wrel1,
                       const float* __restrict__ brel1, float* __restrict__ relc) {
  int c = threadIdx.x;
  float a = brel1[c];
  #pragma unroll 8
  for (int k = 0; k < EMB; ++k) a += mean1[k] * wrel1[c*EMB + k];
  relc[c] = a;
}

__global__ void k_sage1(const float* __restrict__ h0, const float* __restrict__ wroot1,
                        const float* __restrict__ relc, unsigned short* __restrict__ hb) {
  int idx = blockIdx.x * 256 + threadIdx.x;
  int i = idx >> 7, c = idx & 127;
  const float4* hr = (const float4*)(h0 + i*EMB);
  const float4* wr = (const float4*)(wroot1 + c*EMB);
  float a = relc[c];
  #pragma unroll 8
  for (int k = 0; k < EMB/4; ++k) {
    float4 h = hr[k], w = wr[k];
    a += h.x*w.x + h.y*w.y + h.z*w.z + h.w*w.w;
  }
  hb[idx] = f2bf(fmaxf(a, 0.f));
}

// ---------------- fused edge MLP ----------------
// 512 thr = 8 waves, wave w owns fc slice [w*64, w*64+64).
// Weights DMA'd per-wave (global_load_lds, double-buffered, vmcnt(4) counted,
// NO barriers in K-loops). A = weights (m=fc), B = activations (n=edge).
// D: fc = l4*4+reg, edge = l15.  LDS 144KB -> 1 block/CU, 2 waves/SIMD.
__global__ __launch_bounds__(512, 2)
void k_edge_mlp(const unsigned short* __restrict__ hb,
                const unsigned short* __restrict__ w0t,
                const float* __restrict__ lb0,
                const unsigned short* __restrict__ w1t,
                const float* __restrict__ lb1,
                const float* __restrict__ lw2,
                const float* __restrict__ lb2,
                float* __restrict__ out) {
  __shared__ __align__(16) unsigned short e_lds[BM * EMB];    // 16 KB, swz (edge&7)<<4
  __shared__ __align__(16) unsigned short o0_lds[BM * FC];    // 64 KB, swz (edge&7)<<4
  __shared__ __align__(16) unsigned short w_lds[8 * 2 * 2048]; // 64 KB: [wave][buf][2048]

  const int tid  = threadIdx.x;
  const int lane = tid & 63;
  const int wv   = tid >> 6;           // 0..7
  const int l15  = lane & 15;
  const int l4   = lane >> 4;
  const int blk  = blockIdx.x;
  const int fcb  = wv * 64;

  unsigned short* wbuf = w_lds + wv * 4096;     // this wave's 2 buffers

  // prologue: DMA L0 kb0 into buf0
  stage4(w0t + (wv*4 + 0)*2048, wbuf, lane);

  // ---- Phase A: gather h rows, build e tile ----
  {
    int r = tid >> 3, q = tid & 7;
    int k = blk * BM + r;
    float fb = 2.0f * NN - 1.0f;
    float disc = fb*fb - 8.0f*(float)k;
    int i = (int)((fb - sqrtf(disc)) * 0.5f);
    if (i < 0) i = 0;
    if (i > NN-2) i = NN-2;
    while (cum_edges(i+1) <= k) ++i;
    while (cum_edges(i) > k) --i;
    int j = k - cum_edges(i) + i + 1;
    const bf16x8* hi = (const bf16x8*)(hb + i*EMB + q*16);
    const bf16x8* hj = (const bf16x8*)(hb + j*EMB + q*16);
    #pragma unroll
    for (int c = 0; c < 2; ++c) {
      bf16x8 a = hi[c], b = hj[c];
      bf16x8 p;
      #pragma unroll
      for (int u = 0; u < 8; ++u)
        p[u] = (short)f2bf(bf2f((unsigned short)a[u]) * bf2f((unsigned short)b[u]));
      int byt = (r*256 + (q*16 + c*8)*2) ^ ((r & 7) << 4);
      *(bf16x8*)((char*)e_lds + byt) = p;
    }
  }
  __syncthreads();

  // ---- Layer0: K=128 (4 kb), barrier-free pipelined ----
  f32x4 acc[4][4];
  #pragma unroll
  for (int e = 0; e < 4; ++e)
    #pragma unroll
    for (int f = 0; f < 4; ++f)
      acc[e][f] = (f32x4){0.f, 0.f, 0.f, 0.f};

  #pragma unroll
  for (int kb = 0; kb < 4; ++kb) {
    // stage next slice (kb<3: W0 kb+1; kb==3: W1 kb0) into other buffer
    const unsigned short* nsrc = (kb < 3) ? (w0t + (wv*4 + kb + 1)*2048)
                                          : (w1t + (wv*16 + 0)*2048);
    stage4(nsrc, wbuf + ((kb + 1) & 1)*2048, lane);
    asm volatile("s_waitcnt vmcnt(4)" ::: "memory");   // cur slice landed
    const unsigned short* wcur = wbuf + (kb & 1)*2048;
    bf16x8 af[4], bx[4];
    #pragma unroll
    for (int f = 0; f < 4; ++f)
      af[f] = *(const bf16x8*)(wcur + (l4*64 + f*16 + l15)*8);
    #pragma unroll
    for (int e = 0; e < 4; ++e) {
      int ed = e*16 + l15;
      bx[e] = *(const bf16x8*)((const char*)e_lds + ((ed*256 + kb*64 + l4*16) ^ ((ed & 7) << 4)));
    }
    __builtin_amdgcn_s_setprio(1);
    #pragma unroll
    for (int e = 0; e < 4; ++e)
      #pragma unroll
      for (int f = 0; f < 4; ++f)
        acc[e][f] = __builtin_amdgcn_mfma_f32_16x16x32_bf16(af[f], bx[e], acc[e][f], 0, 0, 0);
    __builtin_amdgcn_s_setprio(0);
  }

  // ---- bias + relu + packed o0 store ----
  {
    float4 bv[4];
    #pragma unroll
    for (int f = 0; f < 4; ++f) bv[f] = *(const float4*)(lb0 + fcb + f*16 + l4*4);
    #pragma unroll
    for (int e = 0; e < 4; ++e) {
      int ed = e*16 + l15;
      #pragma unroll
      for (int f = 0; f < 4; ++f) {
        float v0 = fmaxf(acc[e][f][0] + bv[f].x, 0.f);
        float v1 = fmaxf(acc[e][f][1] + bv[f].y, 0.f);
        float v2 = fmaxf(acc[e][f][2] + bv[f].z, 0.f);
        float v3 = fmaxf(acc[e][f][3] + bv[f].w, 0.f);
        unsigned int lo = (unsigned int)f2bf(v0) | ((unsigned int)f2bf(v1) << 16);
        unsigned int hi = (unsigned int)f2bf(v2) | ((unsigned int)f2bf(v3) << 16);
        int byt = (ed*1024 + (fcb + f*16 + l4*4)*2) ^ ((ed & 7) << 4);
        *(uint2*)((char*)o0_lds + byt) = make_uint2(lo, hi);
      }
    }
  }
  __syncthreads();

  // ---- Layer1: K=512 (16 kb), barrier-free pipelined ----
  #pragma unroll
  for (int e = 0; e < 4; ++e)
    #pragma unroll
    for (int f = 0; f < 4; ++f)
      acc[e][f] = (f32x4){0.f, 0.f, 0.f, 0.f};

  #pragma unroll
  for (int kb = 0; kb < 16; ++kb) {
    if (kb < 15) {
      stage4(w1t + (wv*16 + kb + 1)*2048, wbuf + ((kb + 1) & 1)*2048, lane);
      asm volatile("s_waitcnt vmcnt(4)" ::: "memory");
    } else {
      asm volatile("s_waitcnt vmcnt(0)" ::: "memory");
    }
    const unsigned short* wcur = wbuf + (kb & 1)*2048;
    bf16x8 af[4], bx[4];
    #pragma unroll
    for (int f = 0; f < 4; ++f)
      af[f] = *(const bf16x8*)(wcur + (l4*64 + f*16 + l15)*8);
    #pragma unroll
    for (int e = 0; e < 4; ++e) {
      int ed = e*16 + l15;
      bx[e] = *(const bf16x8*)((const char*)o0_lds + ((ed*1024 + kb*64 + l4*16) ^ ((ed & 7) << 4)));
    }
    __builtin_amdgcn_s_setprio(1);
    #pragma unroll
    for (int e = 0; e < 4; ++e)
      #pragma unroll
      for (int f = 0; f < 4; ++f)
        acc[e][f] = __builtin_amdgcn_mfma_f32_16x16x32_bf16(af[f], bx[e], acc[e][f], 0, 0, 0);
    __builtin_amdgcn_s_setprio(0);
  }

  // ---- fused layer2 + sigmoid ----
  {
    float4 l1v[4], l2v[4];
    #pragma unroll
    for (int f = 0; f < 4; ++f) {
      l1v[f] = *(const float4*)(lb1 + fcb + f*16 + l4*4);
      l2v[f] = *(const float4*)(lw2 + fcb + f*16 + l4*4);
    }
    float rs[4] = {0.f, 0.f, 0.f, 0.f};
    #pragma unroll
    for (int e = 0; e < 4; ++e)
      #pragma unroll
      for (int f = 0; f < 4; ++f) {
        rs[e] += fmaxf(acc[e][f][0] + l1v[f].x, 0.f) * l2v[f].x;
        rs[e] += fmaxf(acc[e][f][1] + l1v[f].y, 0.f) * l2v[f].y;
        rs[e] += fmaxf(acc[e][f][2] + l1v[f].z, 0.f) * l2v[f].z;
        rs[e] += fmaxf(acc[e][f][3] + l1v[f].w, 0.f) * l2v[f].w;
      }
    #pragma unroll
    for (int e = 0; e < 4; ++e) {
      rs[e] += __shfl_xor(rs[e], 16, 64);
      rs[e] += __shfl_xor(rs[e], 32, 64);
    }
    float* red = (float*)e_lds;   // e tile dead
    if (l4 == 0) {
      #pragma unroll
      for (int e = 0; e < 4; ++e) red[wv*BM + e*16 + l15] = rs[e];
    }
  }
  __syncthreads();

  if (tid < BM) {
    const float* red = (const float*)e_lds;
    float v = lb2[0];
    #pragma unroll
    for (int w = 0; w < 8; ++w) v += red[w*BM + tid];
    out[blk*BM + tid] = 1.0f / (1.0f + __expf(-v));
  }
}

// ---------------- launch ----------------
extern "C" void kernel_launch(void* const* d_in, const int* in_sizes, int n_in,
                              void* d_out, int out_size, void* d_ws, size_t ws_size,
                              hipStream_t stream) {
  const float* x      = (const float*)d_in[0];
  const float* wrel0  = (const float*)d_in[1];
  const float* brel0  = (const float*)d_in[2];
  const float* wroot0 = (const float*)d_in[3];
  const float* wrel1  = (const float*)d_in[4];
  const float* brel1  = (const float*)d_in[5];
  const float* wroot1 = (const float*)d_in[6];
  const float* lw0    = (const float*)d_in[7];
  const float* lb0    = (const float*)d_in[8];
  const float* lw1    = (const float*)d_in[9];
  const float* lb1    = (const float*)d_in[10];
  const float* lw2    = (const float*)d_in[11];
  const float* lb2    = (const float*)d_in[12];
  float* out = (float*)d_out;

  char* ws = (char*)d_ws;
  unsigned short* hb  = (unsigned short*)(ws);            // 1024*128 bf16
  unsigned short* w0t = (unsigned short*)(ws + 262144);   // 512*128 bf16 tiled
  unsigned short* w1t = (unsigned short*)(ws + 393216);   // 512*512 bf16 tiled
  float* h0    = (float*)(ws + 917504);                   // 1024*128 f32
  float* mean0 = (float*)(ws + 1441792);
  float* mean1 = (float*)(ws + 1441856);
  float* relc  = (float*)(ws + 1442368);

  hipLaunchKernelGGL(k_cvt_weights, dim3(1280), dim3(256), 0, stream, lw0, lw1, w0t, w1t);
  hipLaunchKernelGGL(k_mean_x,   dim3(1),    dim3(256), 0, stream, x, mean0);
  hipLaunchKernelGGL(k_sage0,    dim3(512),  dim3(256), 0, stream, x, wrel0, brel0, wroot0, mean0, h0);
  hipLaunchKernelGGL(k_mean_h0,  dim3(128),  dim3(256), 0, stream, h0, mean1);
  hipLaunchKernelGGL(k_relc,     dim3(1),    dim3(128), 0, stream, mean1, wrel1, brel1, relc);
  hipLaunchKernelGGL(k_sage1,    dim3(512),  dim3(256), 0, stream, h0, wroot1, relc, hb);
  hipLaunchKernelGGL(k_edge_mlp, dim3(NEDGE/BM), dim3(512), 0, stream,
                     hb, w0t, lb0, w1t, lb1, lw2, lb2, out);
}

// Round 5
// 343.420 us; speedup vs baseline: 1.9132x; 1.0800x over previous
//
#include <hip/hip_runtime.h>
#include <math.h>

#define NN 1024
#define EMB 128
#define FC 512
#define NEDGE 523776   // 1024*1023/2
#define BM 64          // edge rows per block; 8184 blocks

typedef __attribute__((ext_vector_type(4))) float f32x4;
typedef __attribute__((ext_vector_type(8))) short bf16x8;

__device__ __forceinline__ float bf2f(unsigned short u) {
  union { unsigned int i; float f; } v; v.i = ((unsigned int)u) << 16; return v.f;
}
__device__ __forceinline__ unsigned short f2bf(float f) {
  union { float g; unsigned int i; } v; v.g = f;
  return (unsigned short)((v.i + 0x7fffu + ((v.i >> 16) & 1u)) >> 16);
}
__device__ __forceinline__ int cum_edges(int i) { return i * NN - ((i * (i + 1)) >> 1); }

// ---------------- setup kernels (tiny) ----------------
// Weight tiling for direct-to-VGPR fragment loads (1 contiguous KB per instr):
// t = f8*(NKB*2048) + kb*2048 + f*512 + ko*128 + l15*8 + e
//   maps to W[f8*64 + f*16 + l15][kb*32 + ko*8 + e]
__global__ void k_cvt_weights(const float* __restrict__ lw0, const float* __restrict__ lw1,
                              unsigned short* __restrict__ w0t, unsigned short* __restrict__ w1t) {
  int t = blockIdx.x * 256 + threadIdx.x;   // 1280 blocks * 256 = 327680 exact
  if (t < 65536) {
    int e = t & 7, l15 = (t >> 3) & 15, ko = (t >> 7) & 3, f = (t >> 9) & 3,
        kb = (t >> 11) & 3, f8 = (t >> 13) & 7;
    w0t[t] = f2bf(lw0[(f8*64 + f*16 + l15)*EMB + kb*32 + ko*8 + e]);
  } else {
    int u = t - 65536;
    int e = u & 7, l15 = (u >> 3) & 15, ko = (u >> 7) & 3, f = (u >> 9) & 3,
        kb = (u >> 11) & 15, f8 = (u >> 15) & 7;
    w1t[u] = f2bf(lw1[(f8*64 + f*16 + l15)*FC + kb*32 + ko*8 + e]);
  }
}

__global__ void k_mean_x(const float* __restrict__ x, float* __restrict__ mean0) {
  __shared__ float sx[256], sy[256];
  float ax = 0.f, ay = 0.f;
  for (int i = threadIdx.x; i < NN; i += 256) { ax += x[2*i]; ay += x[2*i+1]; }
  sx[threadIdx.x] = ax; sy[threadIdx.x] = ay;
  __syncthreads();
  for (int st = 128; st > 0; st >>= 1) {
    if (threadIdx.x < st) { sx[threadIdx.x] += sx[threadIdx.x+st]; sy[threadIdx.x] += sy[threadIdx.x+st]; }
    __syncthreads();
  }
  if (threadIdx.x == 0) { mean0[0] = sx[0] * (1.f/NN); mean0[1] = sy[0] * (1.f/NN); }
}

__global__ void k_sage0(const float* __restrict__ x, const float* __restrict__ wrel,
                        const float* __restrict__ brel, const float* __restrict__ wroot,
                        const float* __restrict__ mean0, float* __restrict__ h0) {
  int idx = blockIdx.x * 256 + threadIdx.x;
  int i = idx >> 7, c = idx & 127;
  float v = mean0[0]*wrel[2*c] + mean0[1]*wrel[2*c+1] + brel[c]
          + x[2*i]*wroot[2*c] + x[2*i+1]*wroot[2*c+1];
  h0[idx] = fmaxf(v, 0.f);
}

__global__ void k_mean_h0(const float* __restrict__ h0, float* __restrict__ mean1) {
  __shared__ float s[256];
  int c = blockIdx.x;
  float a = 0.f;
  for (int i = threadIdx.x; i < NN; i += 256) a += h0[i*EMB + c];
  s[threadIdx.x] = a;
  __syncthreads();
  for (int st = 128; st > 0; st >>= 1) {
    if (threadIdx.x < st) s[threadIdx.x] += s[threadIdx.x+st];
    __syncthreads();
  }
  if (threadIdx.x == 0) mean1[c] = s[0] * (1.f/NN);
}

__global__ void k_relc(const float* __restrict__ mean1, const float* __restrict__ wrel1,
                       const float* __restrict__ brel1, float* __restrict__ relc) {
  int c = threadIdx.x;
  float a = brel1[c];
  #pragma unroll 8
  for (int k = 0; k < EMB; ++k) a += mean1[k] * wrel1[c*EMB + k];
  relc[c] = a;
}

__global__ void k_sage1(const float* __restrict__ h0, const float* __restrict__ wroot1,
                        const float* __restrict__ relc, unsigned short* __restrict__ hb) {
  int idx = blockIdx.x * 256 + threadIdx.x;
  int i = idx >> 7, c = idx & 127;
  const float4* hr = (const float4*)(h0 + i*EMB);
  const float4* wr = (const float4*)(wroot1 + c*EMB);
  float a = relc[c];
  #pragma unroll 8
  for (int k = 0; k < EMB/4; ++k) {
    float4 h = hr[k], w = wr[k];
    a += h.x*w.x + h.y*w.y + h.z*w.z + h.w*w.w;
  }
  hb[idx] = f2bf(fmaxf(a, 0.f));
}

// ---------------- fused edge MLP ----------------
// 512 thr = 8 waves; wave w owns fc slice [w*64, w*64+64) in both layers.
// Weights: direct global->VGPR, double-buffered (a0/a1), 1KB-contiguous per load.
// A = weights (m=fc), B = activations (n=edge); D: fc = l4*4+reg, edge = l15.
// LDS 80KB -> 2 blocks/CU -> 16 waves/CU (needs <=128 combined regs).
__global__ __launch_bounds__(512, 4)
void k_edge_mlp(const unsigned short* __restrict__ hb,
                const unsigned short* __restrict__ w0t,
                const float* __restrict__ lb0,
                const unsigned short* __restrict__ w1t,
                const float* __restrict__ lb1,
                const float* __restrict__ lw2,
                const float* __restrict__ lb2,
                float* __restrict__ out) {
  __shared__ __align__(16) unsigned short e_lds[BM * EMB];    // 16 KB, swz (edge&7)<<4
  __shared__ __align__(16) unsigned short o0_lds[BM * FC];    // 64 KB, swz (edge&7)<<4

  const int tid  = threadIdx.x;
  const int lane = tid & 63;
  const int wv   = tid >> 6;           // 0..7
  const int l15  = lane & 15;
  const int l4   = lane >> 4;
  const int blk  = blockIdx.x;
  const int fcb  = wv * 64;

  const unsigned short* w0w = w0t + wv * 4  * 2048;   // this wave's W0 slices
  const unsigned short* w1w = w1t + wv * 16 * 2048;   // this wave's W1 slices
  const int woff = (l4*16 + l15)*8;                   // lane offset within a slice

  bf16x8 a0[4], a1[4], bx[4];

  // issue-early: L0 kb0 weight fragments
  #pragma unroll
  for (int f = 0; f < 4; ++f)
    a0[f] = *(const bf16x8*)(w0w + f*512 + woff);

  // ---- Phase A: gather h rows, build e tile ----
  {
    int r = tid >> 3, q = tid & 7;
    int k = blk * BM + r;
    float fb = 2.0f * NN - 1.0f;
    float disc = fb*fb - 8.0f*(float)k;
    int i = (int)((fb - sqrtf(disc)) * 0.5f);
    if (i < 0) i = 0;
    if (i > NN-2) i = NN-2;
    while (cum_edges(i+1) <= k) ++i;
    while (cum_edges(i) > k) --i;
    int j = k - cum_edges(i) + i + 1;
    const bf16x8* hi = (const bf16x8*)(hb + i*EMB + q*16);
    const bf16x8* hj = (const bf16x8*)(hb + j*EMB + q*16);
    #pragma unroll
    for (int c = 0; c < 2; ++c) {
      bf16x8 a = hi[c], b = hj[c];
      bf16x8 p;
      #pragma unroll
      for (int u = 0; u < 8; ++u)
        p[u] = (short)f2bf(bf2f((unsigned short)a[u]) * bf2f((unsigned short)b[u]));
      int byt = (r*256 + (q*16 + c*8)*2) ^ ((r & 7) << 4);
      *(bf16x8*)((char*)e_lds + byt) = p;
    }
  }
  __syncthreads();

  // ---- Layer0: K=128 (4 kb), barrier-free, reg-double-buffered weights ----
  f32x4 acc[4][4];
  #pragma unroll
  for (int e = 0; e < 4; ++e)
    #pragma unroll
    for (int f = 0; f < 4; ++f)
      acc[e][f] = (f32x4){0.f, 0.f, 0.f, 0.f};

  #pragma unroll
  for (int kb = 0; kb < 4; kb += 2) {
    #pragma unroll
    for (int f = 0; f < 4; ++f)
      a1[f] = *(const bf16x8*)(w0w + (kb+1)*2048 + f*512 + woff);
    #pragma unroll
    for (int e = 0; e < 4; ++e) {
      int ed = e*16 + l15;
      bx[e] = *(const bf16x8*)((const char*)e_lds + ((ed*256 + kb*64 + l4*16) ^ ((ed & 7) << 4)));
    }
    __builtin_amdgcn_s_setprio(1);
    #pragma unroll
    for (int e = 0; e < 4; ++e)
      #pragma unroll
      for (int f = 0; f < 4; ++f)
        acc[e][f] = __builtin_amdgcn_mfma_f32_16x16x32_bf16(a0[f], bx[e], acc[e][f], 0, 0, 0);
    __builtin_amdgcn_s_setprio(0);
    // prefetch kb+2 (or W1 kb0 at the L0 tail: cross-layer pipeline)
    #pragma unroll
    for (int f = 0; f < 4; ++f)
      a0[f] = (kb + 2 < 4)
            ? *(const bf16x8*)(w0w + (kb+2)*2048 + f*512 + woff)
            : *(const bf16x8*)(w1w + f*512 + woff);
    #pragma unroll
    for (int e = 0; e < 4; ++e) {
      int ed = e*16 + l15;
      bx[e] = *(const bf16x8*)((const char*)e_lds + ((ed*256 + (kb+1)*64 + l4*16) ^ ((ed & 7) << 4)));
    }
    __builtin_amdgcn_s_setprio(1);
    #pragma unroll
    for (int e = 0; e < 4; ++e)
      #pragma unroll
      for (int f = 0; f < 4; ++f)
        acc[e][f] = __builtin_amdgcn_mfma_f32_16x16x32_bf16(a1[f], bx[e], acc[e][f], 0, 0, 0);
    __builtin_amdgcn_s_setprio(0);
  }

  // ---- bias + relu + packed o0 store ----
  {
    float4 bv[4];
    #pragma unroll
    for (int f = 0; f < 4; ++f) bv[f] = *(const float4*)(lb0 + fcb + f*16 + l4*4);
    #pragma unroll
    for (int e = 0; e < 4; ++e) {
      int ed = e*16 + l15;
      #pragma unroll
      for (int f = 0; f < 4; ++f) {
        float v0 = fmaxf(acc[e][f][0] + bv[f].x, 0.f);
        float v1 = fmaxf(acc[e][f][1] + bv[f].y, 0.f);
        float v2 = fmaxf(acc[e][f][2] + bv[f].z, 0.f);
        float v3 = fmaxf(acc[e][f][3] + bv[f].w, 0.f);
        unsigned int lo = (unsigned int)f2bf(v0) | ((unsigned int)f2bf(v1) << 16);
        unsigned int hi = (unsigned int)f2bf(v2) | ((unsigned int)f2bf(v3) << 16);
        int byt = (ed*1024 + (fcb + f*16 + l4*4)*2) ^ ((ed & 7) << 4);
        *(uint2*)((char*)o0_lds + byt) = make_uint2(lo, hi);
      }
    }
  }
  __syncthreads();

  // ---- Layer1: K=512 (16 kb), barrier-free, reg-double-buffered weights ----
  #pragma unroll
  for (int e = 0; e < 4; ++e)
    #pragma unroll
    for (int f = 0; f < 4; ++f)
      acc[e][f] = (f32x4){0.f, 0.f, 0.f, 0.f};

  #pragma unroll
  for (int kb = 0; kb < 16; kb += 2) {
    #pragma unroll
    for (int f = 0; f < 4; ++f)
      a1[f] = *(const bf16x8*)(w1w + (kb+1)*2048 + f*512 + woff);
    #pragma unroll
    for (int e = 0; e < 4; ++e) {
      int ed = e*16 + l15;
      bx[e] = *(const bf16x8*)((const char*)o0_lds + ((ed*1024 + kb*64 + l4*16) ^ ((ed & 7) << 4)));
    }
    __builtin_amdgcn_s_setprio(1);
    #pragma unroll
    for (int e = 0; e < 4; ++e)
      #pragma unroll
      for (int f = 0; f < 4; ++f)
        acc[e][f] = __builtin_amdgcn_mfma_f32_16x16x32_bf16(a0[f], bx[e], acc[e][f], 0, 0, 0);
    __builtin_amdgcn_s_setprio(0);
    if (kb + 2 < 16) {
      #pragma unroll
      for (int f = 0; f < 4; ++f)
        a0[f] = *(const bf16x8*)(w1w + (kb+2)*2048 + f*512 + woff);
    }
    #pragma unroll
    for (int e = 0; e < 4; ++e) {
      int ed = e*16 + l15;
      bx[e] = *(const bf16x8*)((const char*)o0_lds + ((ed*1024 + (kb+1)*64 + l4*16) ^ ((ed & 7) << 4)));
    }
    __builtin_amdgcn_s_setprio(1);
    #pragma unroll
    for (int e = 0; e < 4; ++e)
      #pragma unroll
      for (int f = 0; f < 4; ++f)
        acc[e][f] = __builtin_amdgcn_mfma_f32_16x16x32_bf16(a1[f], bx[e], acc[e][f], 0, 0, 0);
    __builtin_amdgcn_s_setprio(0);
  }

  // ---- fused layer2 + sigmoid ----
  {
    float4 l1v[4], l2v[4];
    #pragma unroll
    for (int f = 0; f < 4; ++f) {
      l1v[f] = *(const float4*)(lb1 + fcb + f*16 + l4*4);
      l2v[f] = *(const float4*)(lw2 + fcb + f*16 + l4*4);
    }
    float rs[4] = {0.f, 0.f, 0.f, 0.f};
    #pragma unroll
    for (int e = 0; e < 4; ++e)
      #pragma unroll
      for (int f = 0; f < 4; ++f) {
        rs[e] += fmaxf(acc[e][f][0] + l1v[f].x, 0.f) * l2v[f].x;
        rs[e] += fmaxf(acc[e][f][1] + l1v[f].y, 0.f) * l2v[f].y;
        rs[e] += fmaxf(acc[e][f][2] + l1v[f].z, 0.f) * l2v[f].z;
        rs[e] += fmaxf(acc[e][f][3] + l1v[f].w, 0.f) * l2v[f].w;
      }
    #pragma unroll
    for (int e = 0; e < 4; ++e) {
      rs[e] += __shfl_xor(rs[e], 16, 64);
      rs[e] += __shfl_xor(rs[e], 32, 64);
    }
    float* red = (float*)e_lds;   // e tile dead
    if (l4 == 0) {
      #pragma unroll
      for (int e = 0; e < 4; ++e) red[wv*BM + e*16 + l15] = rs[e];
    }
  }
  __syncthreads();

  if (tid < BM) {
    const float* red = (const float*)e_lds;
    float v = lb2[0];
    #pragma unroll
    for (int w = 0; w < 8; ++w) v += red[w*BM + tid];
    out[blk*BM + tid] = 1.0f / (1.0f + __expf(-v));
  }
}

// ---------------- launch ----------------
extern "C" void kernel_launch(void* const* d_in, const int* in_sizes, int n_in,
                              void* d_out, int out_size, void* d_ws, size_t ws_size,
                              hipStream_t stream) {
  const float* x      = (const float*)d_in[0];
  const float* wrel0  = (const float*)d_in[1];
  const float* brel0  = (const float*)d_in[2];
  const float* wroot0 = (const float*)d_in[3];
  const float* wrel1  = (const float*)d_in[4];
  const float* brel1  = (const float*)d_in[5];
  const float* wroot1 = (const float*)d_in[6];
  const float* lw0    = (const float*)d_in[7];
  const float* lb0    = (const float*)d_in[8];
  const float* lw1    = (const float*)d_in[9];
  const float* lb1    = (const float*)d_in[10];
  const float* lw2    = (const float*)d_in[11];
  const float* lb2    = (const float*)d_in[12];
  float* out = (float*)d_out;

  char* ws = (char*)d_ws;
  unsigned short* hb  = (unsigned short*)(ws);            // 1024*128 bf16
  unsigned short* w0t = (unsigned short*)(ws + 262144);   // 512*128 bf16 tiled
  unsigned short* w1t = (unsigned short*)(ws + 393216);   // 512*512 bf16 tiled
  float* h0    = (float*)(ws + 917504);                   // 1024*128 f32
  float* mean0 = (float*)(ws + 1441792);
  float* mean1 = (float*)(ws + 1441856);
  float* relc  = (float*)(ws + 1442368);

  hipLaunchKernelGGL(k_cvt_weights, dim3(1280), dim3(256), 0, stream, lw0, lw1, w0t, w1t);
  hipLaunchKernelGGL(k_mean_x,   dim3(1),    dim3(256), 0, stream, x, mean0);
  hipLaunchKernelGGL(k_sage0,    dim3(512),  dim3(256), 0, stream, x, wrel0, brel0, wroot0, mean0, h0);
  hipLaunchKernelGGL(k_mean_h0,  dim3(128),  dim3(256), 0, stream, h0, mean1);
  hipLaunchKernelGGL(k_relc,     dim3(1),    dim3(128), 0, stream, mean1, wrel1, brel1, relc);
  hipLaunchKernelGGL(k_sage1,    dim3(512),  dim3(256), 0, stream, h0, wroot1, relc, hb);
  hipLaunchKernelGGL(k_edge_mlp, dim3(NEDGE/BM), dim3(512), 0, stream,
                     hb, w0t, lb0, w1t, lb1, lw2, lb2, out);
}

// Round 6
// 324.863 us; speedup vs baseline: 2.0225x; 1.0571x over previous
//
#include <hip/hip_runtime.h>
#include <hip/hip_bf16.h>
#include <math.h>

#define NN 1024
#define EMB 128
#define FC 512
#define NEDGE 523776   // 1024*1023/2
#define BM 64          // edge rows per block; 8184 blocks

typedef __attribute__((ext_vector_type(4))) float f32x4;
typedef __attribute__((ext_vector_type(8))) short bf16x8;
typedef __attribute__((ext_vector_type(4))) unsigned int u32x4;

__device__ __forceinline__ float bf2f(unsigned short u) {
  union { unsigned int i; float f; } v; v.i = ((unsigned int)u) << 16; return v.f;
}
// plain cast -> compiler can fuse pairs into v_cvt_pk_bf16_f32 (T12/m240)
__device__ __forceinline__ unsigned short f2bf(float f) {
  return __builtin_bit_cast(unsigned short, __float2bfloat16(f));
}
__device__ __forceinline__ unsigned int pack2bf(float a, float b) {
  return (unsigned int)f2bf(a) | ((unsigned int)f2bf(b) << 16);
}
__device__ __forceinline__ int cum_edges(int i) { return i * NN - ((i * (i + 1)) >> 1); }

// ---------------- setup kernels (tiny) ----------------
// Weight tiling for direct-to-VGPR fragment loads (1 contiguous KB per instr):
// t = f8*(NKB*2048) + kb*2048 + f*512 + ko*128 + l15*8 + e
//   maps to W[f8*64 + f*16 + l15][kb*32 + ko*8 + e]
__global__ void k_cvt_weights(const float* __restrict__ lw0, const float* __restrict__ lw1,
                              unsigned short* __restrict__ w0t, unsigned short* __restrict__ w1t) {
  int t = blockIdx.x * 256 + threadIdx.x;   // 1280 blocks * 256 = 327680 exact
  if (t < 65536) {
    int e = t & 7, l15 = (t >> 3) & 15, ko = (t >> 7) & 3, f = (t >> 9) & 3,
        kb = (t >> 11) & 3, f8 = (t >> 13) & 7;
    w0t[t] = f2bf(lw0[(f8*64 + f*16 + l15)*EMB + kb*32 + ko*8 + e]);
  } else {
    int u = t - 65536;
    int e = u & 7, l15 = (u >> 3) & 15, ko = (u >> 7) & 3, f = (u >> 9) & 3,
        kb = (u >> 11) & 15, f8 = (u >> 15) & 7;
    w1t[u] = f2bf(lw1[(f8*64 + f*16 + l15)*FC + kb*32 + ko*8 + e]);
  }
}

__global__ void k_mean_x(const float* __restrict__ x, float* __restrict__ mean0) {
  __shared__ float sx[256], sy[256];
  float ax = 0.f, ay = 0.f;
  for (int i = threadIdx.x; i < NN; i += 256) { ax += x[2*i]; ay += x[2*i+1]; }
  sx[threadIdx.x] = ax; sy[threadIdx.x] = ay;
  __syncthreads();
  for (int st = 128; st > 0; st >>= 1) {
    if (threadIdx.x < st) { sx[threadIdx.x] += sx[threadIdx.x+st]; sy[threadIdx.x] += sy[threadIdx.x+st]; }
    __syncthreads();
  }
  if (threadIdx.x == 0) { mean0[0] = sx[0] * (1.f/NN); mean0[1] = sy[0] * (1.f/NN); }
}

__global__ void k_sage0(const float* __restrict__ x, const float* __restrict__ wrel,
                        const float* __restrict__ brel, const float* __restrict__ wroot,
                        const float* __restrict__ mean0, float* __restrict__ h0) {
  int idx = blockIdx.x * 256 + threadIdx.x;
  int i = idx >> 7, c = idx & 127;
  float v = mean0[0]*wrel[2*c] + mean0[1]*wrel[2*c+1] + brel[c]
          + x[2*i]*wroot[2*c] + x[2*i+1]*wroot[2*c+1];
  h0[idx] = fmaxf(v, 0.f);
}

__global__ void k_mean_h0(const float* __restrict__ h0, float* __restrict__ mean1) {
  __shared__ float s[256];
  int c = blockIdx.x;
  float a = 0.f;
  for (int i = threadIdx.x; i < NN; i += 256) a += h0[i*EMB + c];
  s[threadIdx.x] = a;
  __syncthreads();
  for (int st = 128; st > 0; st >>= 1) {
    if (threadIdx.x < st) s[threadIdx.x] += s[threadIdx.x+st];
    __syncthreads();
  }
  if (threadIdx.x == 0) mean1[c] = s[0] * (1.f/NN);
}

__global__ void k_relc(const float* __restrict__ mean1, const float* __restrict__ wrel1,
                       const float* __restrict__ brel1, float* __restrict__ relc) {
  int c = threadIdx.x;
  float a = brel1[c];
  #pragma unroll 8
  for (int k = 0; k < EMB; ++k) a += mean1[k] * wrel1[c*EMB + k];
  relc[c] = a;
}

__global__ void k_sage1(const float* __restrict__ h0, const float* __restrict__ wroot1,
                        const float* __restrict__ relc, unsigned short* __restrict__ hb) {
  int idx = blockIdx.x * 256 + threadIdx.x;
  int i = idx >> 7, c = idx & 127;
  const float4* hr = (const float4*)(h0 + i*EMB);
  const float4* wr = (const float4*)(wroot1 + c*EMB);
  float a = relc[c];
  #pragma unroll 8
  for (int k = 0; k < EMB/4; ++k) {
    float4 h = hr[k], w = wr[k];
    a += h.x*w.x + h.y*w.y + h.z*w.z + h.w*w.w;
  }
  hb[idx] = f2bf(fmaxf(a, 0.f));
}

// ---------------- fused edge MLP ----------------
// 512 thr = 8 waves; wave w owns fc slice [w*64, w*64+64) in both layers.
// Weights: direct global->VGPR, double-buffered (a0/a1), 1KB-contiguous per load.
// A = weights (m=fc), B = activations (n=edge); D: fc = l4*4+reg, edge = l15.
// LDS 80KB -> 2 blocks/CU; (512,4) => <=128 unified regs/wave (acc 64 + a 32 + bx 8).
__global__ __launch_bounds__(512, 4)
void k_edge_mlp(const unsigned short* __restrict__ hb,
                const unsigned short* __restrict__ w0t,
                const float* __restrict__ lb0,
                const unsigned short* __restrict__ w1t,
                const float* __restrict__ lb1,
                const float* __restrict__ lw2,
                const float* __restrict__ lb2,
                float* __restrict__ out) {
  __shared__ __align__(16) unsigned short e_lds[BM * EMB];    // 16 KB, swz (edge&7)<<4
  __shared__ __align__(16) unsigned short o0_lds[BM * FC];    // 64 KB, swz (edge&7)<<4

  const int tid  = threadIdx.x;
  const int lane = tid & 63;
  const int wv   = tid >> 6;           // 0..7
  const int l15  = lane & 15;
  const int l4   = lane >> 4;
  const int blk  = blockIdx.x;
  const int fcb  = wv * 64;

  const unsigned short* w0w = w0t + wv * 4  * 2048;   // this wave's W0 slices
  const unsigned short* w1w = w1t + wv * 16 * 2048;   // this wave's W1 slices
  const int woff = (l4*16 + l15)*8;                   // lane offset within a slice

  bf16x8 a0[4], a1[4];

  // issue-early: L0 kb0 weight fragments
  #pragma unroll
  for (int f = 0; f < 4; ++f)
    a0[f] = *(const bf16x8*)(w0w + f*512 + woff);

  // ---- Phase A: gather h rows, build e tile (closed-form i,j; no loops) ----
  {
    int r = tid >> 3, q = tid & 7;
    int k = blk * BM + r;
    float s = sqrtf((float)(4190209 - 8*k));           // (2N-1)^2 - 8k
    int i = (int)((2047.0f - s) * 0.5f);
    if (i < 0) i = 0;
    if (i > NN-2) i = NN-2;
    if (cum_edges(i+1) <= k) ++i;
    if (cum_edges(i+1) <= k) ++i;
    if (cum_edges(i) > k) --i;
    if (cum_edges(i) > k) --i;
    int j = k - cum_edges(i) + i + 1;
    const bf16x8* hi = (const bf16x8*)(hb + i*EMB + q*16);
    const bf16x8* hj = (const bf16x8*)(hb + j*EMB + q*16);
    #pragma unroll
    for (int c = 0; c < 2; ++c) {
      bf16x8 a = hi[c], b = hj[c];
      u32x4 p;
      #pragma unroll
      for (int u = 0; u < 4; ++u) {
        float p0 = bf2f((unsigned short)a[2*u])   * bf2f((unsigned short)b[2*u]);
        float p1 = bf2f((unsigned short)a[2*u+1]) * bf2f((unsigned short)b[2*u+1]);
        p[u] = pack2bf(p0, p1);
      }
      int byt = (r*256 + (q*16 + c*8)*2) ^ ((r & 7) << 4);
      *(u32x4*)((char*)e_lds + byt) = p;
    }
  }
  __syncthreads();

  // ---- Layer0: K=128 (4 kb), barrier-free, reg-double-buffered weights ----
  f32x4 acc[4][4];
  #pragma unroll
  for (int e = 0; e < 4; ++e)
    #pragma unroll
    for (int f = 0; f < 4; ++f)
      acc[e][f] = (f32x4){0.f, 0.f, 0.f, 0.f};

  #pragma unroll
  for (int kb = 0; kb < 4; kb += 2) {
    #pragma unroll
    for (int f = 0; f < 4; ++f)
      a1[f] = *(const bf16x8*)(w0w + (kb+1)*2048 + f*512 + woff);
    {
      bf16x8 b0 = *(const bf16x8*)((const char*)e_lds + (((0*16+l15)*256 + kb*64 + l4*16) ^ ((l15 & 7) << 4)));
      bf16x8 b1 = *(const bf16x8*)((const char*)e_lds + (((1*16+l15)*256 + kb*64 + l4*16) ^ ((l15 & 7) << 4)));
      __builtin_amdgcn_s_setprio(1);
      #pragma unroll
      for (int f = 0; f < 4; ++f) acc[0][f] = __builtin_amdgcn_mfma_f32_16x16x32_bf16(a0[f], b0, acc[0][f], 0, 0, 0);
      #pragma unroll
      for (int f = 0; f < 4; ++f) acc[1][f] = __builtin_amdgcn_mfma_f32_16x16x32_bf16(a0[f], b1, acc[1][f], 0, 0, 0);
      __builtin_amdgcn_s_setprio(0);
      bf16x8 b2 = *(const bf16x8*)((const char*)e_lds + (((2*16+l15)*256 + kb*64 + l4*16) ^ ((l15 & 7) << 4)));
      bf16x8 b3 = *(const bf16x8*)((const char*)e_lds + (((3*16+l15)*256 + kb*64 + l4*16) ^ ((l15 & 7) << 4)));
      __builtin_amdgcn_s_setprio(1);
      #pragma unroll
      for (int f = 0; f < 4; ++f) acc[2][f] = __builtin_amdgcn_mfma_f32_16x16x32_bf16(a0[f], b2, acc[2][f], 0, 0, 0);
      #pragma unroll
      for (int f = 0; f < 4; ++f) acc[3][f] = __builtin_amdgcn_mfma_f32_16x16x32_bf16(a0[f], b3, acc[3][f], 0, 0, 0);
      __builtin_amdgcn_s_setprio(0);
    }
    // prefetch kb+2 (or W1 kb0 at the L0 tail: cross-layer pipeline)
    #pragma unroll
    for (int f = 0; f < 4; ++f)
      a0[f] = (kb + 2 < 4)
            ? *(const bf16x8*)(w0w + (kb+2)*2048 + f*512 + woff)
            : *(const bf16x8*)(w1w + f*512 + woff);
    {
      bf16x8 b0 = *(const bf16x8*)((const char*)e_lds + (((0*16+l15)*256 + (kb+1)*64 + l4*16) ^ ((l15 & 7) << 4)));
      bf16x8 b1 = *(const bf16x8*)((const char*)e_lds + (((1*16+l15)*256 + (kb+1)*64 + l4*16) ^ ((l15 & 7) << 4)));
      __builtin_amdgcn_s_setprio(1);
      #pragma unroll
      for (int f = 0; f < 4; ++f) acc[0][f] = __builtin_amdgcn_mfma_f32_16x16x32_bf16(a1[f], b0, acc[0][f], 0, 0, 0);
      #pragma unroll
      for (int f = 0; f < 4; ++f) acc[1][f] = __builtin_amdgcn_mfma_f32_16x16x32_bf16(a1[f], b1, acc[1][f], 0, 0, 0);
      __builtin_amdgcn_s_setprio(0);
      bf16x8 b2 = *(const bf16x8*)((const char*)e_lds + (((2*16+l15)*256 + (kb+1)*64 + l4*16) ^ ((l15 & 7) << 4)));
      bf16x8 b3 = *(const bf16x8*)((const char*)e_lds + (((3*16+l15)*256 + (kb+1)*64 + l4*16) ^ ((l15 & 7) << 4)));
      __builtin_amdgcn_s_setprio(1);
      #pragma unroll
      for (int f = 0; f < 4; ++f) acc[2][f] = __builtin_amdgcn_mfma_f32_16x16x32_bf16(a1[f], b2, acc[2][f], 0, 0, 0);
      #pragma unroll
      for (int f = 0; f < 4; ++f) acc[3][f] = __builtin_amdgcn_mfma_f32_16x16x32_bf16(a1[f], b3, acc[3][f], 0, 0, 0);
      __builtin_amdgcn_s_setprio(0);
    }
  }

  // ---- bias + relu + packed o0 store (cvt_pk-friendly) ----
  {
    #pragma unroll
    for (int f = 0; f < 4; ++f) {
      float4 bv = *(const float4*)(lb0 + fcb + f*16 + l4*4);
      #pragma unroll
      for (int e = 0; e < 4; ++e) {
        int ed = e*16 + l15;
        float v0 = fmaxf(acc[e][f][0] + bv.x, 0.f);
        float v1 = fmaxf(acc[e][f][1] + bv.y, 0.f);
        float v2 = fmaxf(acc[e][f][2] + bv.z, 0.f);
        float v3 = fmaxf(acc[e][f][3] + bv.w, 0.f);
        unsigned int lo = pack2bf(v0, v1);
        unsigned int hi = pack2bf(v2, v3);
        int byt = (ed*1024 + (fcb + f*16 + l4*4)*2) ^ ((ed & 7) << 4);
        *(uint2*)((char*)o0_lds + byt) = make_uint2(lo, hi);
      }
    }
  }
  __syncthreads();

  // ---- Layer1: K=512 (16 kb), barrier-free, reg-double-buffered weights ----
  #pragma unroll
  for (int e = 0; e < 4; ++e)
    #pragma unroll
    for (int f = 0; f < 4; ++f)
      acc[e][f] = (f32x4){0.f, 0.f, 0.f, 0.f};

  #pragma unroll
  for (int kb = 0; kb < 16; kb += 2) {
    #pragma unroll
    for (int f = 0; f < 4; ++f)
      a1[f] = *(const bf16x8*)(w1w + (kb+1)*2048 + f*512 + woff);
    {
      bf16x8 b0 = *(const bf16x8*)((const char*)o0_lds + (((0*16+l15)*1024 + kb*64 + l4*16) ^ ((l15 & 7) << 4)));
      bf16x8 b1 = *(const bf16x8*)((const char*)o0_lds + (((1*16+l15)*1024 + kb*64 + l4*16) ^ ((l15 & 7) << 4)));
      __builtin_amdgcn_s_setprio(1);
      #pragma unroll
      for (int f = 0; f < 4; ++f) acc[0][f] = __builtin_amdgcn_mfma_f32_16x16x32_bf16(a0[f], b0, acc[0][f], 0, 0, 0);
      #pragma unroll
      for (int f = 0; f < 4; ++f) acc[1][f] = __builtin_amdgcn_mfma_f32_16x16x32_bf16(a0[f], b1, acc[1][f], 0, 0, 0);
      __builtin_amdgcn_s_setprio(0);
      bf16x8 b2 = *(const bf16x8*)((const char*)o0_lds + (((2*16+l15)*1024 + kb*64 + l4*16) ^ ((l15 & 7) << 4)));
      bf16x8 b3 = *(const bf16x8*)((const char*)o0_lds + (((3*16+l15)*1024 + kb*64 + l4*16) ^ ((l15 & 7) << 4)));
      __builtin_amdgcn_s_setprio(1);
      #pragma unroll
      for (int f = 0; f < 4; ++f) acc[2][f] = __builtin_amdgcn_mfma_f32_16x16x32_bf16(a0[f], b2, acc[2][f], 0, 0, 0);
      #pragma unroll
      for (int f = 0; f < 4; ++f) acc[3][f] = __builtin_amdgcn_mfma_f32_16x16x32_bf16(a0[f], b3, acc[3][f], 0, 0, 0);
      __builtin_amdgcn_s_setprio(0);
    }
    if (kb + 2 < 16) {
      #pragma unroll
      for (int f = 0; f < 4; ++f)
        a0[f] = *(const bf16x8*)(w1w + (kb+2)*2048 + f*512 + woff);
    }
    {
      bf16x8 b0 = *(const bf16x8*)((const char*)o0_lds + (((0*16+l15)*1024 + (kb+1)*64 + l4*16) ^ ((l15 & 7) << 4)));
      bf16x8 b1 = *(const bf16x8*)((const char*)o0_lds + (((1*16+l15)*1024 + (kb+1)*64 + l4*16) ^ ((l15 & 7) << 4)));
      __builtin_amdgcn_s_setprio(1);
      #pragma unroll
      for (int f = 0; f < 4; ++f) acc[0][f] = __builtin_amdgcn_mfma_f32_16x16x32_bf16(a1[f], b0, acc[0][f], 0, 0, 0);
      #pragma unroll
      for (int f = 0; f < 4; ++f) acc[1][f] = __builtin_amdgcn_mfma_f32_16x16x32_bf16(a1[f], b1, acc[1][f], 0, 0, 0);
      __builtin_amdgcn_s_setprio(0);
      bf16x8 b2 = *(const bf16x8*)((const char*)o0_lds + (((2*16+l15)*1024 + (kb+1)*64 + l4*16) ^ ((l15 & 7) << 4)));
      bf16x8 b3 = *(const bf16x8*)((const char*)o0_lds + (((3*16+l15)*1024 + (kb+1)*64 + l4*16) ^ ((l15 & 7) << 4)));
      __builtin_amdgcn_s_setprio(1);
      #pragma unroll
      for (int f = 0; f < 4; ++f) acc[2][f] = __builtin_amdgcn_mfma_f32_16x16x32_bf16(a1[f], b2, acc[2][f], 0, 0, 0);
      #pragma unroll
      for (int f = 0; f < 4; ++f) acc[3][f] = __builtin_amdgcn_mfma_f32_16x16x32_bf16(a1[f], b3, acc[3][f], 0, 0, 0);
      __builtin_amdgcn_s_setprio(0);
    }
  }

  // ---- fused layer2 + sigmoid ----
  {
    float rs[4] = {0.f, 0.f, 0.f, 0.f};
    #pragma unroll
    for (int f = 0; f < 4; ++f) {
      float4 l1v = *(const float4*)(lb1 + fcb + f*16 + l4*4);
      float4 l2v = *(const float4*)(lw2 + fcb + f*16 + l4*4);
      #pragma unroll
      for (int e = 0; e < 4; ++e) {
        rs[e] += fmaxf(acc[e][f][0] + l1v.x, 0.f) * l2v.x;
        rs[e] += fmaxf(acc[e][f][1] + l1v.y, 0.f) * l2v.y;
        rs[e] += fmaxf(acc[e][f][2] + l1v.z, 0.f) * l2v.z;
        rs[e] += fmaxf(acc[e][f][3] + l1v.w, 0.f) * l2v.w;
      }
    }
    #pragma unroll
    for (int e = 0; e < 4; ++e) {
      rs[e] += __shfl_xor(rs[e], 16, 64);
      rs[e] += __shfl_xor(rs[e], 32, 64);
    }
    float* red = (float*)e_lds;   // e tile dead
    if (l4 == 0) {
      #pragma unroll
      for (int e = 0; e < 4; ++e) red[wv*BM + e*16 + l15] = rs[e];
    }
  }
  __syncthreads();

  if (tid < BM) {
    const float* red = (const float*)e_lds;
    float v = lb2[0];
    #pragma unroll
    for (int w = 0; w < 8; ++w) v += red[w*BM + tid];
    out[blk*BM + tid] = 1.0f / (1.0f + __expf(-v));
  }
}

// ---------------- launch ----------------
extern "C" void kernel_launch(void* const* d_in, const int* in_sizes, int n_in,
                              void* d_out, int out_size, void* d_ws, size_t ws_size,
                              hipStream_t stream) {
  const float* x      = (const float*)d_in[0];
  const float* wrel0  = (const float*)d_in[1];
  const float* brel0  = (const float*)d_in[2];
  const float* wroot0 = (const float*)d_in[3];
  const float* wrel1  = (const float*)d_in[4];
  const float* brel1  = (const float*)d_in[5];
  const float* wroot1 = (const float*)d_in[6];
  const float* lw0    = (const float*)d_in[7];
  const float* lb0    = (const float*)d_in[8];
  const float* lw1    = (const float*)d_in[9];
  const float* lb1    = (const float*)d_in[10];
  const float* lw2    = (const float*)d_in[11];
  const float* lb2    = (const float*)d_in[12];
  float* out = (float*)d_out;

  char* ws = (char*)d_ws;
  unsigned short* hb  = (unsigned short*)(ws);            // 1024*128 bf16
  unsigned short* w0t = (unsigned short*)(ws + 262144);   // 512*128 bf16 tiled
  unsigned short* w1t = (unsigned short*)(ws + 393216);   // 512*512 bf16 tiled
  float* h0    = (float*)(ws + 917504);                   // 1024*128 f32
  float* mean0 = (float*)(ws + 1441792);
  float* mean1 = (float*)(ws + 1441856);
  float* relc  = (float*)(ws + 1442368);

  hipLaunchKernelGGL(k_cvt_weights, dim3(1280), dim3(256), 0, stream, lw0, lw1, w0t, w1t);
  hipLaunchKernelGGL(k_mean_x,   dim3(1),    dim3(256), 0, stream, x, mean0);
  hipLaunchKernelGGL(k_sage0,    dim3(512),  dim3(256), 0, stream, x, wrel0, brel0, wroot0, mean0, h0);
  hipLaunchKernelGGL(k_mean_h0,  dim3(128),  dim3(256), 0, stream, h0, mean1);
  hipLaunchKernelGGL(k_relc,     dim3(1),    dim3(128), 0, stream, mean1, wrel1, brel1, relc);
  hipLaunchKernelGGL(k_sage1,    dim3(512),  dim3(256), 0, stream, h0, wroot1, relc, hb);
  hipLaunchKernelGGL(k_edge_mlp, dim3(NEDGE/BM), dim3(512), 0, stream,
                     hb, w0t, lb0, w1t, lb1, lw2, lb2, out);
}

// Round 7
// 303.165 us; speedup vs baseline: 2.1673x; 1.0716x over previous
//
#include <hip/hip_runtime.h>
#include <hip/hip_bf16.h>
#include <math.h>

#define NN 1024
#define EMB 128
#define FC 512
#define NEDGE 523776   // 1024*1023/2
#define BM 64          // edge rows per block; 8184 blocks

typedef __attribute__((ext_vector_type(4))) float f32x4;
typedef __attribute__((ext_vector_type(8))) short bf16x8;
typedef __attribute__((ext_vector_type(4))) unsigned int u32x4;

__device__ __forceinline__ float bf2f(unsigned short u) {
  union { unsigned int i; float f; } v; v.i = ((unsigned int)u) << 16; return v.f;
}
__device__ __forceinline__ unsigned short f2bf(float f) {
  return __builtin_bit_cast(unsigned short, __float2bfloat16(f));
}
__device__ __forceinline__ unsigned int pack2bf(float a, float b) {
  return (unsigned int)f2bf(a) | ((unsigned int)f2bf(b) << 16);
}
__device__ __forceinline__ int cum_edges(int i) { return i * NN - ((i * (i + 1)) >> 1); }

// ---------------- setup kernels (tiny) ----------------
// Weight tiling for direct-to-VGPR fragment loads (1 contiguous KB per instr):
// t = f8*(NKB*2048) + kb*2048 + f*512 + ko*128 + l15*8 + e
//   maps to W[f8*64 + f*16 + l15][kb*32 + ko*8 + e]
__global__ void k_cvt_weights(const float* __restrict__ lw0, const float* __restrict__ lw1,
                              unsigned short* __restrict__ w0t, unsigned short* __restrict__ w1t) {
  int t = blockIdx.x * 256 + threadIdx.x;   // 1280 blocks * 256 = 327680 exact
  if (t < 65536) {
    int e = t & 7, l15 = (t >> 3) & 15, ko = (t >> 7) & 3, f = (t >> 9) & 3,
        kb = (t >> 11) & 3, f8 = (t >> 13) & 7;
    w0t[t] = f2bf(lw0[(f8*64 + f*16 + l15)*EMB + kb*32 + ko*8 + e]);
  } else {
    int u = t - 65536;
    int e = u & 7, l15 = (u >> 3) & 15, ko = (u >> 7) & 3, f = (u >> 9) & 3,
        kb = (u >> 11) & 15, f8 = (u >> 15) & 7;
    w1t[u] = f2bf(lw1[(f8*64 + f*16 + l15)*FC + kb*32 + ko*8 + e]);
  }
}

__global__ void k_mean_x(const float* __restrict__ x, float* __restrict__ mean0) {
  __shared__ float sx[256], sy[256];
  float ax = 0.f, ay = 0.f;
  for (int i = threadIdx.x; i < NN; i += 256) { ax += x[2*i]; ay += x[2*i+1]; }
  sx[threadIdx.x] = ax; sy[threadIdx.x] = ay;
  __syncthreads();
  for (int st = 128; st > 0; st >>= 1) {
    if (threadIdx.x < st) { sx[threadIdx.x] += sx[threadIdx.x+st]; sy[threadIdx.x] += sy[threadIdx.x+st]; }
    __syncthreads();
  }
  if (threadIdx.x == 0) { mean0[0] = sx[0] * (1.f/NN); mean0[1] = sy[0] * (1.f/NN); }
}

__global__ void k_sage0(const float* __restrict__ x, const float* __restrict__ wrel,
                        const float* __restrict__ brel, const float* __restrict__ wroot,
                        const float* __restrict__ mean0, float* __restrict__ h0) {
  int idx = blockIdx.x * 256 + threadIdx.x;
  int i = idx >> 7, c = idx & 127;
  float v = mean0[0]*wrel[2*c] + mean0[1]*wrel[2*c+1] + brel[c]
          + x[2*i]*wroot[2*c] + x[2*i+1]*wroot[2*c+1];
  h0[idx] = fmaxf(v, 0.f);
}

__global__ void k_mean_h0(const float* __restrict__ h0, float* __restrict__ mean1) {
  __shared__ float s[256];
  int c = blockIdx.x;
  float a = 0.f;
  for (int i = threadIdx.x; i < NN; i += 256) a += h0[i*EMB + c];
  s[threadIdx.x] = a;
  __syncthreads();
  for (int st = 128; st > 0; st >>= 1) {
    if (threadIdx.x < st) s[threadIdx.x] += s[threadIdx.x+st];
    __syncthreads();
  }
  if (threadIdx.x == 0) mean1[c] = s[0] * (1.f/NN);
}

__global__ void k_relc(const float* __restrict__ mean1, const float* __restrict__ wrel1,
                       const float* __restrict__ brel1, float* __restrict__ relc) {
  int c = threadIdx.x;
  float a = brel1[c];
  #pragma unroll 8
  for (int k = 0; k < EMB; ++k) a += mean1[k] * wrel1[c*EMB + k];
  relc[c] = a;
}

__global__ void k_sage1(const float* __restrict__ h0, const float* __restrict__ wroot1,
                        const float* __restrict__ relc, unsigned short* __restrict__ hb) {
  int idx = blockIdx.x * 256 + threadIdx.x;
  int i = idx >> 7, c = idx & 127;
  const float4* hr = (const float4*)(h0 + i*EMB);
  const float4* wr = (const float4*)(wroot1 + c*EMB);
  float a = relc[c];
  #pragma unroll 8
  for (int k = 0; k < EMB/4; ++k) {
    float4 h = hr[k], w = wr[k];
    a += h.x*w.x + h.y*w.y + h.z*w.z + h.w*w.w;
  }
  hb[idx] = f2bf(fmaxf(a, 0.f));
}

// ---------------- fused edge MLP ----------------
// 512 thr = 8 waves; wave w owns fc slice [w*64, w*64+64) in both layers.
// Activations in LDS stored in MFMA-FRAGMENT ORDER [e_tile][kb][lane][8]:
//   reads are base+lane*16 with compile-time immediate offsets -> zero addr
//   VALU, conflict-free. Biases folded into accumulator init.
// A = weights (m=fc, direct global->VGPR dbuf), B = activations (n=edge).
// D: fc = l4*4+reg, edge = l15. LDS 80KB -> 2 blocks/CU.
__global__ __launch_bounds__(512, 4)
void k_edge_mlp(const unsigned short* __restrict__ hb,
                const unsigned short* __restrict__ w0t,
                const float* __restrict__ lb0,
                const unsigned short* __restrict__ w1t,
                const float* __restrict__ lb1,
                const float* __restrict__ lw2,
                const float* __restrict__ lb2,
                float* __restrict__ out) {
  __shared__ __align__(16) unsigned short e_lds[4*4*64*8];    // 16 KB frag-order
  __shared__ __align__(16) unsigned short o0_lds[4*16*64*8];  // 64 KB frag-order

  const int tid  = threadIdx.x;
  const int lane = tid & 63;
  const int wv   = tid >> 6;           // 0..7
  const int l15  = lane & 15;
  const int l4   = lane >> 4;
  const int blk  = blockIdx.x;
  const int fcb  = wv * 64;

  const unsigned short* w0w = w0t + wv * 4  * 2048;   // this wave's W0 slices
  const unsigned short* w1w = w1t + wv * 16 * 2048;   // this wave's W1 slices
  const int woff = lane * 8;                          // (l4*16+l15)*8

  bf16x8 a0[4], a1[4];

  // issue-early: L0 kb0 weight fragments + L0 bias
  #pragma unroll
  for (int f = 0; f < 4; ++f)
    a0[f] = *(const bf16x8*)(w0w + f*512 + woff);
  float4 b0v[4];
  #pragma unroll
  for (int f = 0; f < 4; ++f) b0v[f] = *(const float4*)(lb0 + fcb + f*16 + l4*4);

  // ---- Phase A: gather h rows, build e tile in fragment order ----
  {
    int r = tid >> 3, q = tid & 7;     // edge row r, k-chunk q (16 k each)
    int k = blk * BM + r;
    float s = sqrtf((float)(4190209 - 8*k));           // (2N-1)^2 - 8k
    int i = (int)((2047.0f - s) * 0.5f);
    if (i < 0) i = 0;
    if (i > NN-2) i = NN-2;
    if (cum_edges(i+1) <= k) ++i;
    if (cum_edges(i+1) <= k) ++i;
    if (cum_edges(i) > k) --i;
    if (cum_edges(i) > k) --i;
    int j = k - cum_edges(i) + i + 1;
    const bf16x8* hi = (const bf16x8*)(hb + i*EMB + q*16);
    const bf16x8* hj = (const bf16x8*)(hb + j*EMB + q*16);
    // dest: [et=r>>4][kb=q>>1][lane = ((q&1)*2+g)*16 + (r&15)][elem = c&7]
    char* wb = (char*)e_lds + ((r>>4)*4096 + (q>>1)*1024 + ((q&1)*32 + (r&15))*16);
    #pragma unroll
    for (int g = 0; g < 2; ++g) {
      bf16x8 a = hi[g], b = hj[g];
      u32x4 p;
      #pragma unroll
      for (int u = 0; u < 4; ++u) {
        float p0 = bf2f((unsigned short)a[2*u])   * bf2f((unsigned short)b[2*u]);
        float p1 = bf2f((unsigned short)a[2*u+1]) * bf2f((unsigned short)b[2*u+1]);
        p[u] = pack2bf(p0, p1);
      }
      *(u32x4*)(wb + g*256) = p;
    }
  }
  __syncthreads();

  const char* rb_e = (const char*)e_lds  + lane*16;
  const char* rb_o = (const char*)o0_lds + lane*16;

  // ---- Layer0: K=128 (4 kb); acc init = bias ----
  f32x4 acc[4][4];
  #pragma unroll
  for (int e = 0; e < 4; ++e)
    #pragma unroll
    for (int f = 0; f < 4; ++f)
      acc[e][f] = (f32x4){b0v[f].x, b0v[f].y, b0v[f].z, b0v[f].w};

  #pragma unroll
  for (int kb = 0; kb < 4; kb += 2) {
    bf16x8 bx[4];
    #pragma unroll
    for (int f = 0; f < 4; ++f)
      a1[f] = *(const bf16x8*)(w0w + (kb+1)*2048 + f*512 + woff);
    #pragma unroll
    for (int e = 0; e < 4; ++e)
      bx[e] = *(const bf16x8*)(rb_e + e*4096 + kb*1024);
    __builtin_amdgcn_s_setprio(1);
    #pragma unroll
    for (int e = 0; e < 4; ++e)
      #pragma unroll
      for (int f = 0; f < 4; ++f)
        acc[e][f] = __builtin_amdgcn_mfma_f32_16x16x32_bf16(a0[f], bx[e], acc[e][f], 0, 0, 0);
    __builtin_amdgcn_s_setprio(0);
    // prefetch kb+2 (or W1 kb0 at the L0 tail: cross-layer pipeline)
    #pragma unroll
    for (int f = 0; f < 4; ++f)
      a0[f] = (kb + 2 < 4)
            ? *(const bf16x8*)(w0w + (kb+2)*2048 + f*512 + woff)
            : *(const bf16x8*)(w1w + f*512 + woff);
    #pragma unroll
    for (int e = 0; e < 4; ++e)
      bx[e] = *(const bf16x8*)(rb_e + e*4096 + (kb+1)*1024);
    __builtin_amdgcn_s_setprio(1);
    #pragma unroll
    for (int e = 0; e < 4; ++e)
      #pragma unroll
      for (int f = 0; f < 4; ++f)
        acc[e][f] = __builtin_amdgcn_mfma_f32_16x16x32_bf16(a1[f], bx[e], acc[e][f], 0, 0, 0);
    __builtin_amdgcn_s_setprio(0);
  }

  // L1 bias (load early, overlaps o0 store)
  float4 b1v[4];
  #pragma unroll
  for (int f = 0; f < 4; ++f) b1v[f] = *(const float4*)(lb1 + fcb + f*16 + l4*4);

  // ---- relu + packed o0 store in fragment order ----
  // value (fc = fcb+f*16+l4*4+rg, edge = e*16+l15) ->
  //   [et=e][kb=wv*2+(f>>1)][lane=((f&1)*2+(l4>>1))*16+l15][elem=(l4&1)*4+rg]
  {
    char* wb = (char*)o0_lds + (wv*2048 + ((l4>>1)*16 + l15)*16 + (l4&1)*8);
    #pragma unroll
    for (int f = 0; f < 4; ++f) {
      #pragma unroll
      for (int e = 0; e < 4; ++e) {
        float v0 = fmaxf(acc[e][f][0], 0.f);
        float v1 = fmaxf(acc[e][f][1], 0.f);
        float v2 = fmaxf(acc[e][f][2], 0.f);
        float v3 = fmaxf(acc[e][f][3], 0.f);
        *(uint2*)(wb + e*16384 + (f>>1)*1024 + (f&1)*512) =
            make_uint2(pack2bf(v0, v1), pack2bf(v2, v3));
      }
    }
  }
  __syncthreads();

  // ---- Layer1: K=512 (16 kb); acc init = bias ----
  #pragma unroll
  for (int e = 0; e < 4; ++e)
    #pragma unroll
    for (int f = 0; f < 4; ++f)
      acc[e][f] = (f32x4){b1v[f].x, b1v[f].y, b1v[f].z, b1v[f].w};

  #pragma unroll
  for (int kb = 0; kb < 16; kb += 2) {
    bf16x8 bx[4];
    #pragma unroll
    for (int f = 0; f < 4; ++f)
      a1[f] = *(const bf16x8*)(w1w + (kb+1)*2048 + f*512 + woff);
    #pragma unroll
    for (int e = 0; e < 4; ++e)
      bx[e] = *(const bf16x8*)(rb_o + e*16384 + kb*1024);
    __builtin_amdgcn_s_setprio(1);
    #pragma unroll
    for (int e = 0; e < 4; ++e)
      #pragma unroll
      for (int f = 0; f < 4; ++f)
        acc[e][f] = __builtin_amdgcn_mfma_f32_16x16x32_bf16(a0[f], bx[e], acc[e][f], 0, 0, 0);
    __builtin_amdgcn_s_setprio(0);
    if (kb + 2 < 16) {
      #pragma unroll
      for (int f = 0; f < 4; ++f)
        a0[f] = *(const bf16x8*)(w1w + (kb+2)*2048 + f*512 + woff);
    }
    #pragma unroll
    for (int e = 0; e < 4; ++e)
      bx[e] = *(const bf16x8*)(rb_o + e*16384 + (kb+1)*1024);
    __builtin_amdgcn_s_setprio(1);
    #pragma unroll
    for (int e = 0; e < 4; ++e)
      #pragma unroll
      for (int f = 0; f < 4; ++f)
        acc[e][f] = __builtin_amdgcn_mfma_f32_16x16x32_bf16(a1[f], bx[e], acc[e][f], 0, 0, 0);
    __builtin_amdgcn_s_setprio(0);
  }

  // ---- fused layer2 + sigmoid (bias already in acc) ----
  {
    float rs[4] = {0.f, 0.f, 0.f, 0.f};
    #pragma unroll
    for (int f = 0; f < 4; ++f) {
      float4 l2v = *(const float4*)(lw2 + fcb + f*16 + l4*4);
      #pragma unroll
      for (int e = 0; e < 4; ++e) {
        rs[e] += fmaxf(acc[e][f][0], 0.f) * l2v.x;
        rs[e] += fmaxf(acc[e][f][1], 0.f) * l2v.y;
        rs[e] += fmaxf(acc[e][f][2], 0.f) * l2v.z;
        rs[e] += fmaxf(acc[e][f][3], 0.f) * l2v.w;
      }
    }
    #pragma unroll
    for (int e = 0; e < 4; ++e) {
      rs[e] += __shfl_xor(rs[e], 16, 64);
      rs[e] += __shfl_xor(rs[e], 32, 64);
    }
    float* red = (float*)e_lds;   // e tile dead (all waves past L0 barrier)
    if (l4 == 0) {
      #pragma unroll
      for (int e = 0; e < 4; ++e) red[wv*BM + e*16 + l15] = rs[e];
    }
  }
  __syncthreads();

  if (tid < BM) {
    const float* red = (const float*)e_lds;
    float v = lb2[0];
    #pragma unroll
    for (int w = 0; w < 8; ++w) v += red[w*BM + tid];
    out[blk*BM + tid] = 1.0f / (1.0f + __expf(-v));
  }
}

// ---------------- launch ----------------
extern "C" void kernel_launch(void* const* d_in, const int* in_sizes, int n_in,
                              void* d_out, int out_size, void* d_ws, size_t ws_size,
                              hipStream_t stream) {
  const float* x      = (const float*)d_in[0];
  const float* wrel0  = (const float*)d_in[1];
  const float* brel0  = (const float*)d_in[2];
  const float* wroot0 = (const float*)d_in[3];
  const float* wrel1  = (const float*)d_in[4];
  const float* brel1  = (const float*)d_in[5];
  const float* wroot1 = (const float*)d_in[6];
  const float* lw0    = (const float*)d_in[7];
  const float* lb0    = (const float*)d_in[8];
  const float* lw1    = (const float*)d_in[9];
  const float* lb1    = (const float*)d_in[10];
  const float* lw2    = (const float*)d_in[11];
  const float* lb2    = (const float*)d_in[12];
  float* out = (float*)d_out;

  char* ws = (char*)d_ws;
  unsigned short* hb  = (unsigned short*)(ws);            // 1024*128 bf16
  unsigned short* w0t = (unsigned short*)(ws + 262144);   // 512*128 bf16 tiled
  unsigned short* w1t = (unsigned short*)(ws + 393216);   // 512*512 bf16 tiled
  float* h0    = (float*)(ws + 917504);                   // 1024*128 f32
  float* mean0 = (float*)(ws + 1441792);
  float* mean1 = (float*)(ws + 1441856);
  float* relc  = (float*)(ws + 1442368);

  hipLaunchKernelGGL(k_cvt_weights, dim3(1280), dim3(256), 0, stream, lw0, lw1, w0t, w1t);
  hipLaunchKernelGGL(k_mean_x,   dim3(1),    dim3(256), 0, stream, x, mean0);
  hipLaunchKernelGGL(k_sage0,    dim3(512),  dim3(256), 0, stream, x, wrel0, brel0, wroot0, mean0, h0);
  hipLaunchKernelGGL(k_mean_h0,  dim3(128),  dim3(256), 0, stream, h0, mean1);
  hipLaunchKernelGGL(k_relc,     dim3(1),    dim3(128), 0, stream, mean1, wrel1, brel1, relc);
  hipLaunchKernelGGL(k_sage1,    dim3(512),  dim3(256), 0, stream, h0, wroot1, relc, hb);
  hipLaunchKernelGGL(k_edge_mlp, dim3(NEDGE/BM), dim3(512), 0, stream,
                     hb, w0t, lb0, w1t, lb1, lw2, lb2, out);
}

// Round 8
// 218.737 us; speedup vs baseline: 3.0038x; 1.3860x over previous
//
#include <hip/hip_runtime.h>
#include <hip/hip_bf16.h>
#include <math.h>

#define NN 1024
#define EMB 128
#define FC 512
#define NEDGE 523776   // 1024*1023/2
#define BM 64          // edge rows per block; 8184 blocks

typedef __attribute__((ext_vector_type(4))) float f32x4;
typedef __attribute__((ext_vector_type(8))) short bf16x8;
typedef __attribute__((ext_vector_type(4))) unsigned int u32x4;
typedef __attribute__((ext_vector_type(8))) int i32x8;

__device__ __forceinline__ float bf2f(unsigned short u) {
  union { unsigned int i; float f; } v; v.i = ((unsigned int)u) << 16; return v.f;
}
__device__ __forceinline__ unsigned short f2bf(float f) {
  return __builtin_bit_cast(unsigned short, __float2bfloat16(f));
}
__device__ __forceinline__ int cum_edges(int i) { return i * NN - ((i * (i + 1)) >> 1); }

// pack 4 f32 -> 4 fp8(e4m3 OCP) in one dword (bytes in order a,b,c,d)
__device__ __forceinline__ unsigned int pk4_fp8(float a, float b, float c, float d) {
  int v = __builtin_amdgcn_cvt_pk_fp8_f32(a, b, 0, false);
  v = __builtin_amdgcn_cvt_pk_fp8_f32(c, d, v, true);
  return (unsigned int)v;
}
__device__ __forceinline__ i32x8 mk8(u32x4 lo, u32x4 hi) {
  i32x8 r;
  r[0]=(int)lo[0]; r[1]=(int)lo[1]; r[2]=(int)lo[2]; r[3]=(int)lo[3];
  r[4]=(int)hi[0]; r[5]=(int)hi[1]; r[6]=(int)hi[2]; r[7]=(int)hi[3];
  return r;
}
// scales = 1.0 (e8m0 byte 127) for both operands -> plain fp8 matmul, K=128
#define MFMA_FP8(A,B,C) __builtin_amdgcn_mfma_scale_f32_16x16x128_f8f6f4((A),(B),(C),0,0,0,0x7f7f7f7f,0,0x7f7f7f7f)

// ---------------- setup kernels (tiny) ----------------
// fp8 weight tiles, pre-scaled by 2^6. Layout (dwords):
// W0: d = wv*2048 + f*512 + lane*8 + dw  ->  W0[wv*64+f*16+(lane&15)][(lane>>4)*32+dw*4 ..+4)
// W1: d = wv*8192 + kb*2048 + f*512 + lane*8 + dw -> W1[wv*64+f*16+(lane&15)][kb*128+(lane>>4)*32+dw*4 ..)
__global__ void k_cvt_weights(const float* __restrict__ lw0, const float* __restrict__ lw1,
                              unsigned int* __restrict__ w0q, unsigned int* __restrict__ w1q) {
  int d = blockIdx.x * 256 + threadIdx.x;   // 320 blocks * 256 = 81920 dwords exact
  if (d < 16384) {
    int dw = d & 7, lane = (d >> 3) & 63, f = (d >> 9) & 3, wv = d >> 11;
    int fc = wv*64 + f*16 + (lane & 15);
    int k  = (lane >> 4)*32 + dw*4;
    float4 s = *(const float4*)(lw0 + fc*EMB + k);
    w0q[d] = pk4_fp8(s.x*64.f, s.y*64.f, s.z*64.f, s.w*64.f);
  } else {
    int u = d - 16384;
    int dw = u & 7, lane = (u >> 3) & 63, f = (u >> 9) & 3, kb = (u >> 11) & 3, wv = u >> 13;
    int fc = wv*64 + f*16 + (lane & 15);
    int k  = kb*128 + (lane >> 4)*32 + dw*4;
    float4 s = *(const float4*)(lw1 + fc*FC + k);
    w1q[u] = pk4_fp8(s.x*64.f, s.y*64.f, s.z*64.f, s.w*64.f);
  }
}

__global__ void k_mean_x(const float* __restrict__ x, float* __restrict__ mean0) {
  __shared__ float sx[256], sy[256];
  float ax = 0.f, ay = 0.f;
  for (int i = threadIdx.x; i < NN; i += 256) { ax += x[2*i]; ay += x[2*i+1]; }
  sx[threadIdx.x] = ax; sy[threadIdx.x] = ay;
  __syncthreads();
  for (int st = 128; st > 0; st >>= 1) {
    if (threadIdx.x < st) { sx[threadIdx.x] += sx[threadIdx.x+st]; sy[threadIdx.x] += sy[threadIdx.x+st]; }
    __syncthreads();
  }
  if (threadIdx.x == 0) { mean0[0] = sx[0] * (1.f/NN); mean0[1] = sy[0] * (1.f/NN); }
}

__global__ void k_sage0(const float* __restrict__ x, const float* __restrict__ wrel,
                        const float* __restrict__ brel, const float* __restrict__ wroot,
                        const float* __restrict__ mean0, float* __restrict__ h0) {
  int idx = blockIdx.x * 256 + threadIdx.x;
  int i = idx >> 7, c = idx & 127;
  float v = mean0[0]*wrel[2*c] + mean0[1]*wrel[2*c+1] + brel[c]
          + x[2*i]*wroot[2*c] + x[2*i+1]*wroot[2*c+1];
  h0[idx] = fmaxf(v, 0.f);
}

__global__ void k_mean_h0(const float* __restrict__ h0, float* __restrict__ mean1) {
  __shared__ float s[256];
  int c = blockIdx.x;
  float a = 0.f;
  for (int i = threadIdx.x; i < NN; i += 256) a += h0[i*EMB + c];
  s[threadIdx.x] = a;
  __syncthreads();
  for (int st = 128; st > 0; st >>= 1) {
    if (threadIdx.x < st) s[threadIdx.x] += s[threadIdx.x+st];
    __syncthreads();
  }
  if (threadIdx.x == 0) mean1[c] = s[0] * (1.f/NN);
}

__global__ void k_relc(const float* __restrict__ mean1, const float* __restrict__ wrel1,
                       const float* __restrict__ brel1, float* __restrict__ relc) {
  int c = threadIdx.x;
  float a = brel1[c];
  #pragma unroll 8
  for (int k = 0; k < EMB; ++k) a += mean1[k] * wrel1[c*EMB + k];
  relc[c] = a;
}

// hb pre-scaled by 32 -> edge products carry 2^10
__global__ void k_sage1(const float* __restrict__ h0, const float* __restrict__ wroot1,
                        const float* __restrict__ relc, unsigned short* __restrict__ hb) {
  int idx = blockIdx.x * 256 + threadIdx.x;
  int i = idx >> 7, c = idx & 127;
  const float4* hr = (const float4*)(h0 + i*EMB);
  const float4* wr = (const float4*)(wroot1 + c*EMB);
  float a = relc[c];
  #pragma unroll 8
  for (int k = 0; k < EMB/4; ++k) {
    float4 h = hr[k], w = wr[k];
    a += h.x*w.x + h.y*w.y + h.z*w.z + h.w*w.w;
  }
  hb[idx] = f2bf(fmaxf(a, 0.f) * 32.0f);
}

// ---------------- fused edge MLP (full fp8, K=128 MFMA) ----------------
// 8 waves; wave w owns fc slice [w*64, w*64+64) in both layers.
// A = weights (m=fc), B = activations (n=edge); D: fc=l4*4+reg, edge=l15.
// fp8 frags: lane row=l15, k=(lane>>4)*32+[0..32) linear bytes (8 dwords).
// Scales: e=2^10 (hb*32), W=2^6, o0=2^7; descale 2^-9 (L0) / 2^-13 (final).
// LDS 40KB; (512,4) -> 2 blocks/CU.
__global__ __launch_bounds__(512, 4)
void k_edge_mlp(const unsigned short* __restrict__ hb,
                const unsigned int* __restrict__ w0q,
                const float* __restrict__ lb0,
                const unsigned int* __restrict__ w1q,
                const float* __restrict__ lb1,
                const float* __restrict__ lw2,
                const float* __restrict__ lb2,
                float* __restrict__ out) {
  __shared__ __align__(16) unsigned int e_lds[2048];    // 8 KB  [et(4)][half(2)][lane(64)][16B]
  __shared__ __align__(16) unsigned int o0_lds[8192];   // 32 KB [et(4)][kb(4)][half(2)][lane(64)][16B]

  const int tid  = threadIdx.x;
  const int lane = tid & 63;
  const int wv   = tid >> 6;           // 0..7
  const int l15  = lane & 15;
  const int l4   = lane >> 4;
  const int blk  = blockIdx.x;
  const int fcb  = wv * 64;

  const char* w0w = (const char*)(w0q + wv * 2048);   // 8 KB/wave
  const char* w1w = (const char*)(w1q + wv * 8192);   // 32 KB/wave

  // ---- Phase A: gather h rows, build e tile (fp8, frag order) ----
  {
    int r = tid >> 3, q = tid & 7;     // edge row r, k-chunk q (16 k each)
    int k = blk * BM + r;
    float s = sqrtf((float)(4190209 - 8*k));           // (2N-1)^2 - 8k
    int i = (int)((2047.0f - s) * 0.5f);
    if (i < 0) i = 0;
    if (i > NN-2) i = NN-2;
    if (cum_edges(i+1) <= k) ++i;
    if (cum_edges(i+1) <= k) ++i;
    if (cum_edges(i) > k) --i;
    if (cum_edges(i) > k) --i;
    int j = k - cum_edges(i) + i + 1;
    const bf16x8* hi = (const bf16x8*)(hb + i*EMB + q*16);
    const bf16x8* hj = (const bf16x8*)(hb + j*EMB + q*16);
    float p[16];
    #pragma unroll
    for (int g = 0; g < 2; ++g) {
      bf16x8 a = hi[g], b = hj[g];
      #pragma unroll
      for (int u = 0; u < 8; ++u)
        p[g*8+u] = bf2f((unsigned short)a[u]) * bf2f((unsigned short)b[u]);
    }
    u32x4 d;
    #pragma unroll
    for (int u = 0; u < 4; ++u)
      d[u] = pk4_fp8(p[4*u], p[4*u+1], p[4*u+2], p[4*u+3]);
    int byt = (r>>4)*2048 + (q&1)*1024 + ((q>>1)*16 + (r&15))*16;
    *(u32x4*)((char*)e_lds + byt) = d;
  }
  __syncthreads();

  // ---- Layer0: K=128 = one fp8 MFMA per tile; acc init = b0 * 2^16 ----
  i32x8 a[4];
  {
    #pragma unroll
    for (int f = 0; f < 4; ++f) {
      u32x4 lo = *(const u32x4*)(w0w + f*2048 + lane*32);
      u32x4 hi = *(const u32x4*)(w0w + f*2048 + lane*32 + 16);
      a[f] = mk8(lo, hi);
    }
  }
  f32x4 acc[4][4];
  {
    #pragma unroll
    for (int f = 0; f < 4; ++f) {
      float4 bv = *(const float4*)(lb0 + fcb + f*16 + l4*4);
      #pragma unroll
      for (int e = 0; e < 4; ++e)
        acc[e][f] = (f32x4){bv.x*65536.f, bv.y*65536.f, bv.z*65536.f, bv.w*65536.f};
    }
  }
  {
    const char* rbe = (const char*)e_lds + lane*16;
    #pragma unroll
    for (int e = 0; e < 4; ++e) {
      u32x4 lo = *(const u32x4*)(rbe + e*2048);
      u32x4 hi = *(const u32x4*)(rbe + e*2048 + 1024);
      i32x8 b = mk8(lo, hi);
      __builtin_amdgcn_s_setprio(1);
      #pragma unroll
      for (int f = 0; f < 4; ++f)
        acc[e][f] = MFMA_FP8(a[f], b, acc[e][f]);
      __builtin_amdgcn_s_setprio(0);
    }
  }

  // ---- relu + fp8 o0 store in frag order (o0 scale 2^7: acc*2^-9) ----
  {
    const float c9 = 0.001953125f;   // 2^-9
    char* ob = (char*)o0_lds + (wv>>1)*2048 + (wv&1)*512 + l15*16 + l4*4;
    #pragma unroll
    for (int f = 0; f < 4; ++f) {
      #pragma unroll
      for (int e = 0; e < 4; ++e) {
        unsigned int d = pk4_fp8(fmaxf(acc[e][f][0], 0.f)*c9,
                                 fmaxf(acc[e][f][1], 0.f)*c9,
                                 fmaxf(acc[e][f][2], 0.f)*c9,
                                 fmaxf(acc[e][f][3], 0.f)*c9);
        *(unsigned int*)(ob + e*8192 + (f&1)*1024 + (f>>1)*256) = d;
      }
    }
  }
  __syncthreads();

  // ---- Layer1: K=512 = 4 fp8 kb; acc init = b1 * 2^13 ----
  {
    #pragma unroll
    for (int f = 0; f < 4; ++f) {
      float4 bv = *(const float4*)(lb1 + fcb + f*16 + l4*4);
      #pragma unroll
      for (int e = 0; e < 4; ++e)
        acc[e][f] = (f32x4){bv.x*8192.f, bv.y*8192.f, bv.z*8192.f, bv.w*8192.f};
    }
  }
  {
    const char* rbo = (const char*)o0_lds + lane*16;
    #pragma unroll
    for (int kb = 0; kb < 4; ++kb) {
      #pragma unroll
      for (int f = 0; f < 4; ++f) {
        u32x4 lo = *(const u32x4*)(w1w + kb*8192 + f*2048 + lane*32);
        u32x4 hi = *(const u32x4*)(w1w + kb*8192 + f*2048 + lane*32 + 16);
        a[f] = mk8(lo, hi);
      }
      #pragma unroll
      for (int e = 0; e < 4; ++e) {
        u32x4 lo = *(const u32x4*)(rbo + e*8192 + kb*2048);
        u32x4 hi = *(const u32x4*)(rbo + e*8192 + kb*2048 + 1024);
        i32x8 b = mk8(lo, hi);
        __builtin_amdgcn_s_setprio(1);
        #pragma unroll
        for (int f = 0; f < 4; ++f)
          acc[e][f] = MFMA_FP8(a[f], b, acc[e][f]);
        __builtin_amdgcn_s_setprio(0);
      }
    }
  }

  // ---- fused layer2 + sigmoid (descale 2^-13) ----
  {
    float rs[4] = {0.f, 0.f, 0.f, 0.f};
    #pragma unroll
    for (int f = 0; f < 4; ++f) {
      float4 l2v = *(const float4*)(lw2 + fcb + f*16 + l4*4);
      #pragma unroll
      for (int e = 0; e < 4; ++e) {
        rs[e] += fmaxf(acc[e][f][0], 0.f) * l2v.x;
        rs[e] += fmaxf(acc[e][f][1], 0.f) * l2v.y;
        rs[e] += fmaxf(acc[e][f][2], 0.f) * l2v.z;
        rs[e] += fmaxf(acc[e][f][3], 0.f) * l2v.w;
      }
    }
    const float c13 = 1.220703125e-4f;   // 2^-13
    #pragma unroll
    for (int e = 0; e < 4; ++e) {
      rs[e] += __shfl_xor(rs[e], 16, 64);
      rs[e] += __shfl_xor(rs[e], 32, 64);
      rs[e] *= c13;
    }
    float* red = (float*)e_lds;   // e tile dead (all waves past o0 barrier)
    if (l4 == 0) {
      #pragma unroll
      for (int e = 0; e < 4; ++e) red[wv*BM + e*16 + l15] = rs[e];
    }
  }
  __syncthreads();

  if (tid < BM) {
    const float* red = (const float*)e_lds;
    float v = lb2[0];
    #pragma unroll
    for (int w = 0; w < 8; ++w) v += red[w*BM + tid];
    out[blk*BM + tid] = 1.0f / (1.0f + __expf(-v));
  }
}

// ---------------- launch ----------------
extern "C" void kernel_launch(void* const* d_in, const int* in_sizes, int n_in,
                              void* d_out, int out_size, void* d_ws, size_t ws_size,
                              hipStream_t stream) {
  const float* x      = (const float*)d_in[0];
  const float* wrel0  = (const float*)d_in[1];
  const float* brel0  = (const float*)d_in[2];
  const float* wroot0 = (const float*)d_in[3];
  const float* wrel1  = (const float*)d_in[4];
  const float* brel1  = (const float*)d_in[5];
  const float* wroot1 = (const float*)d_in[6];
  const float* lw0    = (const float*)d_in[7];
  const float* lb0    = (const float*)d_in[8];
  const float* lw1    = (const float*)d_in[9];
  const float* lb1    = (const float*)d_in[10];
  const float* lw2    = (const float*)d_in[11];
  const float* lb2    = (const float*)d_in[12];
  float* out = (float*)d_out;

  char* ws = (char*)d_ws;
  unsigned short* hb  = (unsigned short*)(ws);            // 1024*128 bf16 (262144 B)
  unsigned int*   w0q = (unsigned int*)(ws + 262144);     // W0 fp8 tiled (65536 B)
  unsigned int*   w1q = (unsigned int*)(ws + 327680);     // W1 fp8 tiled (262144 B)
  float* h0    = (float*)(ws + 589824);                   // 1024*128 f32 (524288 B)
  float* mean0 = (float*)(ws + 1114112);
  float* mean1 = (float*)(ws + 1114176);
  float* relc  = (float*)(ws + 1114688);

  hipLaunchKernelGGL(k_cvt_weights, dim3(320), dim3(256), 0, stream, lw0, lw1, w0q, w1q);
  hipLaunchKernelGGL(k_mean_x,   dim3(1),    dim3(256), 0, stream, x, mean0);
  hipLaunchKernelGGL(k_sage0,    dim3(512),  dim3(256), 0, stream, x, wrel0, brel0, wroot0, mean0, h0);
  hipLaunchKernelGGL(k_mean_h0,  dim3(128),  dim3(256), 0, stream, h0, mean1);
  hipLaunchKernelGGL(k_relc,     dim3(1),    dim3(128), 0, stream, mean1, wrel1, brel1, relc);
  hipLaunchKernelGGL(k_sage1,    dim3(512),  dim3(256), 0, stream, h0, wroot1, relc, hb);
  hipLaunchKernelGGL(k_edge_mlp, dim3(NEDGE/BM), dim3(512), 0, stream,
                     hb, w0q, lb0, w1q, lb1, lw2, lb2, out);
}

// Round 9
// 218.197 us; speedup vs baseline: 3.0112x; 1.0025x over previous
//
#include <hip/hip_runtime.h>
#include <hip/hip_bf16.h>
#include <math.h>

#define NN 1024
#define EMB 128
#define FC 512
#define NEDGE 523776   // 1024*1023/2
#define BM 64          // edge rows per block; 8184 blocks

typedef __attribute__((ext_vector_type(4))) float f32x4;
typedef __attribute__((ext_vector_type(8))) short bf16x8;
typedef __attribute__((ext_vector_type(4))) unsigned int u32x4;
typedef __attribute__((ext_vector_type(8))) int i32x8;

__device__ __forceinline__ float bf2f(unsigned short u) {
  union { unsigned int i; float f; } v; v.i = ((unsigned int)u) << 16; return v.f;
}
__device__ __forceinline__ unsigned short f2bf(float f) {
  return __builtin_bit_cast(unsigned short, __float2bfloat16(f));
}
__device__ __forceinline__ int cum_edges(int i) { return i * NN - ((i * (i + 1)) >> 1); }

// pack 4 f32 -> 4 fp8(e4m3 OCP) in one dword (bytes in order a,b,c,d)
__device__ __forceinline__ unsigned int pk4_fp8(float a, float b, float c, float d) {
  int v = __builtin_amdgcn_cvt_pk_fp8_f32(a, b, 0, false);
  v = __builtin_amdgcn_cvt_pk_fp8_f32(c, d, v, true);
  return (unsigned int)v;
}
// fp8 MFMA K=128 with uniform power-of-2 scale folded into the instruction.
// Uniform 2^s on either operand scales D by 2^s -> operand-order-safe.
// L0: s=-9  (0x76...)  acc = 2^7 * preact  (o0 fp8 convention)
// L1: s=-13 (0x72...)  acc = true preact
#define MFMA_FP8_L0(A,B,C) __builtin_amdgcn_mfma_scale_f32_16x16x128_f8f6f4((A),(B),(C),0,0,0,0x76767676,0,0x7f7f7f7f)
#define MFMA_FP8_L1(A,B,C) __builtin_amdgcn_mfma_scale_f32_16x16x128_f8f6f4((A),(B),(C),0,0,0,0x72727272,0,0x7f7f7f7f)

// ---------------- setup kernels (tiny) ----------------
// fp8 weight tiles, pre-scaled by 2^6. Layout (dwords):
// W0: d = wv*2048 + f*512 + lane*8 + dw  ->  W0[wv*64+f*16+(lane&15)][(lane>>4)*32+dw*4 ..+4)
// W1: d = wv*8192 + kb*2048 + f*512 + lane*8 + dw -> W1[wv*64+f*16+(lane&15)][kb*128+(lane>>4)*32+dw*4 ..)
__global__ void k_cvt_weights(const float* __restrict__ lw0, const float* __restrict__ lw1,
                              unsigned int* __restrict__ w0q, unsigned int* __restrict__ w1q) {
  int d = blockIdx.x * 256 + threadIdx.x;   // 320 blocks * 256 = 81920 dwords exact
  if (d < 16384) {
    int dw = d & 7, lane = (d >> 3) & 63, f = (d >> 9) & 3, wv = d >> 11;
    int fc = wv*64 + f*16 + (lane & 15);
    int k  = (lane >> 4)*32 + dw*4;
    float4 s = *(const float4*)(lw0 + fc*EMB + k);
    w0q[d] = pk4_fp8(s.x*64.f, s.y*64.f, s.z*64.f, s.w*64.f);
  } else {
    int u = d - 16384;
    int dw = u & 7, lane = (u >> 3) & 63, f = (u >> 9) & 3, kb = (u >> 11) & 3, wv = u >> 13;
    int fc = wv*64 + f*16 + (lane & 15);
    int k  = kb*128 + (lane >> 4)*32 + dw*4;
    float4 s = *(const float4*)(lw1 + fc*FC + k);
    w1q[u] = pk4_fp8(s.x*64.f, s.y*64.f, s.z*64.f, s.w*64.f);
  }
}

__global__ void k_mean_x(const float* __restrict__ x, float* __restrict__ mean0) {
  __shared__ float sx[256], sy[256];
  float ax = 0.f, ay = 0.f;
  for (int i = threadIdx.x; i < NN; i += 256) { ax += x[2*i]; ay += x[2*i+1]; }
  sx[threadIdx.x] = ax; sy[threadIdx.x] = ay;
  __syncthreads();
  for (int st = 128; st > 0; st >>= 1) {
    if (threadIdx.x < st) { sx[threadIdx.x] += sx[threadIdx.x+st]; sy[threadIdx.x] += sy[threadIdx.x+st]; }
    __syncthreads();
  }
  if (threadIdx.x == 0) { mean0[0] = sx[0] * (1.f/NN); mean0[1] = sy[0] * (1.f/NN); }
}

__global__ void k_sage0(const float* __restrict__ x, const float* __restrict__ wrel,
                        const float* __restrict__ brel, const float* __restrict__ wroot,
                        const float* __restrict__ mean0, float* __restrict__ h0) {
  int idx = blockIdx.x * 256 + threadIdx.x;
  int i = idx >> 7, c = idx & 127;
  float v = mean0[0]*wrel[2*c] + mean0[1]*wrel[2*c+1] + brel[c]
          + x[2*i]*wroot[2*c] + x[2*i+1]*wroot[2*c+1];
  h0[idx] = fmaxf(v, 0.f);
}

__global__ void k_mean_h0(const float* __restrict__ h0, float* __restrict__ mean1) {
  __shared__ float s[256];
  int c = blockIdx.x;
  float a = 0.f;
  for (int i = threadIdx.x; i < NN; i += 256) a += h0[i*EMB + c];
  s[threadIdx.x] = a;
  __syncthreads();
  for (int st = 128; st > 0; st >>= 1) {
    if (threadIdx.x < st) s[threadIdx.x] += s[threadIdx.x+st];
    __syncthreads();
  }
  if (threadIdx.x == 0) mean1[c] = s[0] * (1.f/NN);
}

__global__ void k_relc(const float* __restrict__ mean1, const float* __restrict__ wrel1,
                       const float* __restrict__ brel1, float* __restrict__ relc) {
  int c = threadIdx.x;
  float a = brel1[c];
  #pragma unroll 8
  for (int k = 0; k < EMB; ++k) a += mean1[k] * wrel1[c*EMB + k];
  relc[c] = a;
}

// hb pre-scaled by 32 -> edge products carry 2^10
__global__ void k_sage1(const float* __restrict__ h0, const float* __restrict__ wroot1,
                        const float* __restrict__ relc, unsigned short* __restrict__ hb) {
  int idx = blockIdx.x * 256 + threadIdx.x;
  int i = idx >> 7, c = idx & 127;
  const float4* hr = (const float4*)(h0 + i*EMB);
  const float4* wr = (const float4*)(wroot1 + c*EMB);
  float a = relc[c];
  #pragma unroll 8
  for (int k = 0; k < EMB/4; ++k) {
    float4 h = hr[k], w = wr[k];
    a += h.x*w.x + h.y*w.y + h.z*w.z + h.w*w.w;
  }
  hb[idx] = f2bf(fmaxf(a, 0.f) * 32.0f);
}

// ---------------- fused edge MLP (full fp8, K=128 MFMA) ----------------
// 8 waves; wave w owns fc slice [w*64, w*64+64) in both layers.
// A = weights (m=fc), B = activations (n=edge); D: fc=l4*4+reg, edge=l15.
// Scales: e=2^10 (hb*32), W=2^6, o0=2^7; descales folded into MFMA scale op.
// LDS 40KB; (512,4) -> 2 blocks/CU.
__global__ __launch_bounds__(512, 4)
void k_edge_mlp(const unsigned short* __restrict__ hb,
                const unsigned int* __restrict__ w0q,
                const float* __restrict__ lb0,
                const unsigned int* __restrict__ w1q,
                const float* __restrict__ lb1,
                const float* __restrict__ lw2,
                const float* __restrict__ lb2,
                float* __restrict__ out) {
  __shared__ __align__(16) unsigned int e_lds[2048];    // 8 KB  [et(4)][half(2)][lane(64)][16B]
  __shared__ __align__(16) unsigned int o0_lds[8192];   // 32 KB [et(4)][kb(4)][half(2)][lane(64)][16B]

  const int tid  = threadIdx.x;
  const int lane = tid & 63;
  const int wv   = tid >> 6;           // 0..7
  const int l15  = lane & 15;
  const int l4   = lane >> 4;
  const int blk  = blockIdx.x;
  const int fcb  = wv * 64;

  const char* w0w = (const char*)(w0q + wv * 2048);   // 8 KB/wave
  const char* w1w = (const char*)(w1q + wv * 8192);   // 32 KB/wave

  // ---- Phase A: gather h rows, build e tile (fp8, frag order) ----
  {
    int r = tid >> 3, q = tid & 7;     // edge row r, k-chunk q (16 k each)
    int k = blk * BM + r;
    float s = sqrtf((float)(4190209 - 8*k));           // (2N-1)^2 - 8k
    int i = (int)((2047.0f - s) * 0.5f);
    if (i < 0) i = 0;
    if (i > NN-2) i = NN-2;
    if (cum_edges(i+1) <= k) ++i;
    if (cum_edges(i+1) <= k) ++i;
    if (cum_edges(i) > k) --i;
    if (cum_edges(i) > k) --i;
    int j = k - cum_edges(i) + i + 1;
    const bf16x8* hi = (const bf16x8*)(hb + i*EMB + q*16);
    const bf16x8* hj = (const bf16x8*)(hb + j*EMB + q*16);
    float p[16];
    #pragma unroll
    for (int g = 0; g < 2; ++g) {
      bf16x8 a = hi[g], b = hj[g];
      #pragma unroll
      for (int u = 0; u < 8; ++u)
        p[g*8+u] = bf2f((unsigned short)a[u]) * bf2f((unsigned short)b[u]);
    }
    u32x4 d;
    #pragma unroll
    for (int u = 0; u < 4; ++u)
      d[u] = pk4_fp8(p[4*u], p[4*u+1], p[4*u+2], p[4*u+3]);
    int byt = (r>>4)*2048 + (q&1)*1024 + ((q>>1)*16 + (r&15))*16;
    *(u32x4*)((char*)e_lds + byt) = d;
  }
  __syncthreads();

  // ---- Layer0: K=128 = one fp8 MFMA per tile; acc init = b0 * 2^7 ----
  i32x8 a[4];
  #pragma unroll
  for (int f = 0; f < 4; ++f) {
    *(u32x4*)&a[f]       = *(const u32x4*)(w0w + f*2048 + lane*32);
    *((u32x4*)&a[f] + 1) = *(const u32x4*)(w0w + f*2048 + lane*32 + 16);
  }
  f32x4 acc[4][4];
  #pragma unroll
  for (int f = 0; f < 4; ++f) {
    float4 bv = *(const float4*)(lb0 + fcb + f*16 + l4*4);
    #pragma unroll
    for (int e = 0; e < 4; ++e)
      acc[e][f] = (f32x4){bv.x*128.f, bv.y*128.f, bv.z*128.f, bv.w*128.f};
  }
  {
    const char* rbe = (const char*)e_lds + lane*16;
    #pragma unroll
    for (int e = 0; e < 4; ++e) {
      i32x8 b;
      *(u32x4*)&b       = *(const u32x4*)(rbe + e*2048);
      *((u32x4*)&b + 1) = *(const u32x4*)(rbe + e*2048 + 1024);
      __builtin_amdgcn_s_setprio(1);
      #pragma unroll
      for (int f = 0; f < 4; ++f)
        acc[e][f] = MFMA_FP8_L0(a[f], b, acc[e][f]);
      __builtin_amdgcn_s_setprio(0);
    }
  }

  // ---- relu + fp8 o0 store in frag order (acc already at 2^7 scale) ----
  {
    char* ob = (char*)o0_lds + (wv>>1)*2048 + (wv&1)*512 + l15*16 + l4*4;
    #pragma unroll
    for (int f = 0; f < 4; ++f) {
      #pragma unroll
      for (int e = 0; e < 4; ++e) {
        unsigned int d = pk4_fp8(fmaxf(acc[e][f][0], 0.f),
                                 fmaxf(acc[e][f][1], 0.f),
                                 fmaxf(acc[e][f][2], 0.f),
                                 fmaxf(acc[e][f][3], 0.f));
        *(unsigned int*)(ob + e*8192 + (f&1)*1024 + (f>>1)*256) = d;
      }
    }
  }
  __syncthreads();

  // ---- Layer1: K=512 = 4 fp8 kb; acc init = b1 (true scale) ----
  #pragma unroll
  for (int f = 0; f < 4; ++f) {
    float4 bv = *(const float4*)(lb1 + fcb + f*16 + l4*4);
    #pragma unroll
    for (int e = 0; e < 4; ++e)
      acc[e][f] = (f32x4){bv.x, bv.y, bv.z, bv.w};
  }
  {
    const char* rbo = (const char*)o0_lds + lane*16;
    #pragma unroll
    for (int kb = 0; kb < 4; ++kb) {
      #pragma unroll
      for (int f = 0; f < 4; ++f) {
        *(u32x4*)&a[f]       = *(const u32x4*)(w1w + kb*8192 + f*2048 + lane*32);
        *((u32x4*)&a[f] + 1) = *(const u32x4*)(w1w + kb*8192 + f*2048 + lane*32 + 16);
      }
      #pragma unroll
      for (int e = 0; e < 4; ++e) {
        i32x8 b;
        *(u32x4*)&b       = *(const u32x4*)(rbo + e*8192 + kb*2048);
        *((u32x4*)&b + 1) = *(const u32x4*)(rbo + e*8192 + kb*2048 + 1024);
        __builtin_amdgcn_s_setprio(1);
        #pragma unroll
        for (int f = 0; f < 4; ++f)
          acc[e][f] = MFMA_FP8_L1(a[f], b, acc[e][f]);
        __builtin_amdgcn_s_setprio(0);
      }
    }
  }

  // ---- fused layer2 + sigmoid (acc at true scale) ----
  {
    float rs[4] = {0.f, 0.f, 0.f, 0.f};
    #pragma unroll
    for (int f = 0; f < 4; ++f) {
      float4 l2v = *(const float4*)(lw2 + fcb + f*16 + l4*4);
      #pragma unroll
      for (int e = 0; e < 4; ++e) {
        rs[e] += fmaxf(acc[e][f][0], 0.f) * l2v.x;
        rs[e] += fmaxf(acc[e][f][1], 0.f) * l2v.y;
        rs[e] += fmaxf(acc[e][f][2], 0.f) * l2v.z;
        rs[e] += fmaxf(acc[e][f][3], 0.f) * l2v.w;
      }
    }
    #pragma unroll
    for (int e = 0; e < 4; ++e) {
      rs[e] += __shfl_xor(rs[e], 16, 64);
      rs[e] += __shfl_xor(rs[e], 32, 64);
    }
    float* red = (float*)e_lds;   // e tile dead (all waves past o0 barrier)
    if (l4 == 0) {
      #pragma unroll
      for (int e = 0; e < 4; ++e) red[wv*BM + e*16 + l15] = rs[e];
    }
  }
  __syncthreads();

  if (tid < BM) {
    const float* red = (const float*)e_lds;
    float v = lb2[0];
    #pragma unroll
    for (int w = 0; w < 8; ++w) v += red[w*BM + tid];
    out[blk*BM + tid] = 1.0f / (1.0f + __expf(-v));
  }
}

// ---------------- launch ----------------
extern "C" void kernel_launch(void* const* d_in, const int* in_sizes, int n_in,
                              void* d_out, int out_size, void* d_ws, size_t ws_size,
                              hipStream_t stream) {
  const float* x      = (const float*)d_in[0];
  const float* wrel0  = (const float*)d_in[1];
  const float* brel0  = (const float*)d_in[2];
  const float* wroot0 = (const float*)d_in[3];
  const float* wrel1  = (const float*)d_in[4];
  const float* brel1  = (const float*)d_in[5];
  const float* wroot1 = (const float*)d_in[6];
  const float* lw0    = (const float*)d_in[7];
  const float* lb0    = (const float*)d_in[8];
  const float* lw1    = (const float*)d_in[9];
  const float* lb1    = (const float*)d_in[10];
  const float* lw2    = (const float*)d_in[11];
  const float* lb2    = (const float*)d_in[12];
  float* out = (float*)d_out;

  char* ws = (char*)d_ws;
  unsigned short* hb  = (unsigned short*)(ws);            // 1024*128 bf16 (262144 B)
  unsigned int*   w0q = (unsigned int*)(ws + 262144);     // W0 fp8 tiled (65536 B)
  unsigned int*   w1q = (unsigned int*)(ws + 327680);     // W1 fp8 tiled (262144 B)
  float* h0    = (float*)(ws + 589824);                   // 1024*128 f32 (524288 B)
  float* mean0 = (float*)(ws + 1114112);
  float* mean1 = (float*)(ws + 1114176);
  float* relc  = (float*)(ws + 1114688);

  hipLaunchKernelGGL(k_cvt_weights, dim3(320), dim3(256), 0, stream, lw0, lw1, w0q, w1q);
  hipLaunchKernelGGL(k_mean_x,   dim3(1),    dim3(256), 0, stream, x, mean0);
  hipLaunchKernelGGL(k_sage0,    dim3(512),  dim3(256), 0, stream, x, wrel0, brel0, wroot0, mean0, h0);
  hipLaunchKernelGGL(k_mean_h0,  dim3(128),  dim3(256), 0, stream, h0, mean1);
  hipLaunchKernelGGL(k_relc,     dim3(1),    dim3(128), 0, stream, mean1, wrel1, brel1, relc);
  hipLaunchKernelGGL(k_sage1,    dim3(512),  dim3(256), 0, stream, h0, wroot1, relc, hb);
  hipLaunchKernelGGL(k_edge_mlp, dim3(NEDGE/BM), dim3(512), 0, stream,
                     hb, w0q, lb0, w1q, lb1, lw2, lb2, out);
}